// Round 9
// baseline (1753.741 us; speedup 1.0000x reference)
//
#include <hip/hip_runtime.h>

// GNN1: 3x GraphConv(add) + linear head on MI355X.
// R6 CSR build; R7 agg (109us, mem-system wall); R8-R10 sliced agg LOSS;
// R11 dbuf neutral; R12 chunk-major LOSS; R13 XOR swizzle + counted-vmcnt
// ring neutral (733us); R14 full-fp8 GEMM FAILED accuracy (328 > 129).
// R15: HYBRID split-K GEMM for layers 2/3: 8 fp8 steps (BK=64) over the
// h|W_root half (h already fp8 in the gather buffer -> no added A error;
// W_root fp8 per-col) THEN one acc rescale (x s_h*sB[c]) THEN 16 bf16
// steps over agg|W_rel (precision-critical agg term unchanged vs R13).
// 24 K-steps vs 32; h1/h2 bf16 writes stay dropped.

typedef unsigned short u16;
typedef unsigned int u32;
typedef unsigned char u8;
typedef long i64;

#define NN 50000
#define NE 1600000
#define MPAD 50176
#define GRID_M ((NN + 127) / 128)  // 391
#define NBKT 98
#define CAP 20480
#define STG 18432

using frag8 = __attribute__((ext_vector_type(8))) short;
using f32x4 = __attribute__((ext_vector_type(4))) float;
using f32x2 = __attribute__((ext_vector_type(2))) float;

__device__ __forceinline__ u16 f2bf(float f) {
  u32 u = __float_as_uint(f);
  u32 r = u + 0x7fffu + ((u >> 16) & 1u);
  return (u16)(r >> 16);
}
__device__ __forceinline__ float lo2f(u32 u) { return __uint_as_float(u << 16); }
__device__ __forceinline__ float hi2f(u32 u) { return __uint_as_float(u & 0xffff0000u); }
__device__ __forceinline__ u32 pack2(float a, float b) {
  return (u32)f2bf(a) | ((u32)f2bf(b) << 16);
}

__device__ __forceinline__ void g2l16(const void* g, void* l) {
  __builtin_amdgcn_global_load_lds((const __attribute__((address_space(1))) void*)g,
                                   (__attribute__((address_space(3))) void*)l, 16, 0, 0);
}

// 16B-slot XOR swizzle (involution): chunk bits[1:0] ^= bits[4:3].
__device__ __forceinline__ int swz(int s) { return s ^ ((s >> 3) & 3); }

// ---------------- binned CSR build ----------------

__global__ void zero_i32(int* p, int n) {
  int i = blockIdx.x * 256 + threadIdx.x;
  if (i < n) p[i] = 0;
}

__global__ __launch_bounds__(256) void p1bin(const int* __restrict__ src,
                                             const int* __restrict__ dst,
                                             int* __restrict__ gcur,
                                             u32* __restrict__ region, int ne) {
  __shared__ u32 lbuf[NBKT * 64];
  __shared__ int lcnt[NBKT];
  __shared__ int gbase[NBKT];
  const int tid = threadIdx.x;
  if (tid < NBKT) lcnt[tid] = 0;
  __syncthreads();
  const int base = blockIdx.x * 2048;
#pragma unroll
  for (int j = 0; j < 8; ++j) {
    int i = base + j * 256 + tid;
    if (i < ne) {
      int d = dst[i];
      int s = src[i];
      int b = d >> 9;
      u32 entry = ((u32)(d & 511) << 16) | (u32)s;
      int slot = atomicAdd(&lcnt[b], 1);
      if (slot < 64) lbuf[b * 64 + slot] = entry;
      else {
        int g = atomicAdd(&gcur[b], 1);
        region[(size_t)b * CAP + g] = entry;
      }
    }
  }
  __syncthreads();
  if (tid < NBKT) {
    int c = min(lcnt[tid], 64);
    gbase[tid] = atomicAdd(&gcur[tid], c);
  }
  __syncthreads();
  const int wv = tid >> 6, lane = tid & 63;
  for (int b = wv; b < NBKT; b += 4) {
    int c = min(lcnt[b], 64);
    int gb = gbase[b];
    for (int s2 = lane; s2 < c; s2 += 64)
      region[(size_t)b * CAP + gb + s2] = lbuf[b * 64 + s2];
  }
}

__global__ void scan98(const int* __restrict__ gcur, int* __restrict__ bbase,
                       int* __restrict__ rs) {
  if (threadIdx.x == 0) {
    int run = 0;
    for (int b = 0; b < NBKT; ++b) {
      bbase[b] = run;
      run += gcur[b];
    }
    bbase[NBKT] = run;
    rs[NN] = run;
  }
}

__global__ __launch_bounds__(256) void p2build(const u32* __restrict__ region,
                                               const int* __restrict__ gcnt,
                                               const int* __restrict__ bbase,
                                               int* __restrict__ rs,
                                               u16* __restrict__ csr) {
  __shared__ int cnt[512];
  __shared__ int off[512];
  __shared__ int sh[256];
  __shared__ u16 stg[STG];
  const int b = blockIdx.x, tid = threadIdx.x;
  const int n0 = b * 512;
  const int nnb = min(512, NN - n0);
  const int ec = gcnt[b];
  const int gb = bbase[b];
  const u32* __restrict__ reg = region + (size_t)b * CAP;
  cnt[tid] = 0;
  cnt[tid + 256] = 0;
  __syncthreads();
  for (int i = tid; i < ec; i += 256) atomicAdd(&cnt[reg[i] >> 16], 1);
  __syncthreads();
  int c0 = cnt[2 * tid], c1 = cnt[2 * tid + 1];
  int s = c0 + c1;
  sh[tid] = s;
  __syncthreads();
  for (int o = 1; o < 256; o <<= 1) {
    int t2 = (tid >= o) ? sh[tid - o] : 0;
    __syncthreads();
    sh[tid] += t2;
    __syncthreads();
  }
  int base0 = sh[tid] - s;
  off[2 * tid] = base0;
  off[2 * tid + 1] = base0 + c0;
  __syncthreads();
  if (2 * tid < nnb) rs[n0 + 2 * tid] = gb + off[2 * tid];
  if (2 * tid + 1 < nnb) rs[n0 + 2 * tid + 1] = gb + off[2 * tid + 1];
  cnt[2 * tid] = off[2 * tid];
  cnt[2 * tid + 1] = off[2 * tid + 1];
  __syncthreads();
  for (int i = tid; i < ec; i += 256) {
    u32 e = reg[i];
    int slot = atomicAdd(&cnt[e >> 16], 1);
    u16 sv = (u16)(e & 0xffff);
    if (slot < STG) stg[slot] = sv;
    else csr[gb + slot] = sv;
  }
  __syncthreads();
  for (int i = tid; i < ec && i < STG; i += 256) csr[gb + i] = stg[i];
}

// ---------------- dtype conversion ----------------

__global__ void f2bf_x(const float4* __restrict__ in, u16* __restrict__ out, int n4) {
  int i = blockIdx.x * 256 + threadIdx.x;
  if (i < n4) {
    float4 v = in[i];
    int node = i >> 5;
    int w = i & 31;
    uint2 o;
    o.x = pack2(v.x, v.y);
    o.y = pack2(v.z, v.w);
    *(uint2*)(out + (size_t)node * 256 + 128 + w * 4) = o;
  }
}

__global__ void wtrans(const float* __restrict__ Wa, int Ka, const float* __restrict__ Wb,
                       int Kb, int N, u16* __restrict__ out) {
  int idx = blockIdx.x * 256 + threadIdx.x;
  int Kt = Ka + Kb;
  if (idx >= N * Kt) return;
  int n = idx / Kt;
  int k = idx - n * Kt;
  float v = (k < Ka) ? Wa[(size_t)k * N + n] : Wb[(size_t)(k - Ka) * N + n];
  out[idx] = f2bf(v);
}

// W [512 x N] f32 -> fp8 out[n][512] with per-col scale. One wave per col.
__global__ __launch_bounds__(256) void wtransf8(const float* __restrict__ W, int N,
                                                u8* __restrict__ out,
                                                float* __restrict__ sB) {
  int n = blockIdx.x * 4 + (threadIdx.x >> 6);
  int lane = threadIdx.x & 63;
  if (n >= N) return;
  float v[8];
  float m = 0.f;
#pragma unroll
  for (int j = 0; j < 8; ++j) {
    float x = W[(size_t)(lane * 8 + j) * N + n];
    v[j] = x;
    m = fmaxf(m, fabsf(x));
  }
#pragma unroll
  for (int o = 1; o < 64; o <<= 1) m = fmaxf(m, __shfl_xor(m, o));
  float inv = (m > 0.f) ? 448.f / m : 0.f;
  uint2 o2;
  u32 lo0 = (u32)__builtin_amdgcn_cvt_pk_fp8_f32(v[0] * inv, v[1] * inv, 0, false);
  u32 hi0 = (u32)__builtin_amdgcn_cvt_pk_fp8_f32(v[2] * inv, v[3] * inv, 0, false);
  u32 lo1 = (u32)__builtin_amdgcn_cvt_pk_fp8_f32(v[4] * inv, v[5] * inv, 0, false);
  u32 hi1 = (u32)__builtin_amdgcn_cvt_pk_fp8_f32(v[6] * inv, v[7] * inv, 0, false);
  o2.x = (lo0 & 0xffffu) | (hi0 << 16);
  o2.y = (lo1 & 0xffffu) | (hi1 << 16);
  *(uint2*)(out + (size_t)n * 512 + lane * 8) = o2;
  if (lane == 0) sB[n] = (m > 0.f) ? m / 448.f : 1.0f;
}

// ---------------- layer-1 aggregation: bf16, 128 dims ----------------

__device__ __forceinline__ void accb(f32x2* a, uint4 v, float s) {
  f32x2 sv = (f32x2){s, s};
  f32x2 f;
  f.x = lo2f(v.x); f.y = hi2f(v.x); a[0] += f * sv;
  f.x = lo2f(v.y); f.y = hi2f(v.y); a[1] += f * sv;
  f.x = lo2f(v.z); f.y = hi2f(v.z); a[2] += f * sv;
  f.x = lo2f(v.w); f.y = hi2f(v.w); a[3] += f * sv;
}

__global__ __launch_bounds__(256) void agg_bf128(const u16* __restrict__ H, int ldh,
                                                 u16* __restrict__ Out, int ldo,
                                                 const int* __restrict__ rs,
                                                 const u16* __restrict__ csr, int n) {
  int w = (blockIdx.x * 256 + threadIdx.x) >> 6;
  int lane = threadIdx.x & 63;
  if (w >= n) return;
  int beg = rs[w], end = rs[w + 1];
  const int q = lane >> 4;
  const int lsub = lane & 15;
  f32x2 acc[4];
#pragma unroll
  for (int i = 0; i < 4; ++i) acc[i] = (f32x2){0.f, 0.f};

  int e = beg;
  for (; e + 16 <= end; e += 16) {
    int si[4];
#pragma unroll
    for (int u = 0; u < 4; ++u) si[u] = csr[e + 4 * u + q];
    uint4 v[4];
#pragma unroll
    for (int u = 0; u < 4; ++u)
      v[u] = *(const uint4*)(H + (size_t)si[u] * ldh + lsub * 8);
#pragma unroll
    for (int u = 0; u < 4; ++u) accb(acc, v[u], 1.f);
  }
  if (e < end) {
#pragma unroll
    for (int u = 0; u < 4; ++u) {
      int ei = e + 4 * u + q;
      int ec = min(ei, end - 1);
      int s0 = csr[ec];
      uint4 v = *(const uint4*)(H + (size_t)s0 * ldh + lsub * 8);
      accb(acc, v, (ei < end) ? 1.f : 0.f);
    }
  }
#pragma unroll
  for (int i = 0; i < 4; ++i) {
    acc[i].x += __shfl_xor(acc[i].x, 16);
    acc[i].y += __shfl_xor(acc[i].y, 16);
    acc[i].x += __shfl_xor(acc[i].x, 32);
    acc[i].y += __shfl_xor(acc[i].y, 32);
  }
  if (lane < 32) {
    int qq = lane >> 4;
    uint2 o;
    o.x = pack2(acc[qq * 2].x, acc[qq * 2].y);
    o.y = pack2(acc[qq * 2 + 1].x, acc[qq * 2 + 1].y);
    *(uint2*)(Out + (size_t)w * ldo + (lane & 15) * 8 + qq * 4) = o;
  }
}

// ---------------- 512-dim aggregation: fp8 in -> bf16 out ----------------

__device__ __forceinline__ void accp(f32x2* a, uint4 v, float s) {
  f32x2 sv = (f32x2){s, s};
  f32x2 f;
  f = __builtin_amdgcn_cvt_pk_f32_fp8(v.x, false); a[0] += f * sv;
  f = __builtin_amdgcn_cvt_pk_f32_fp8(v.x, true);  a[1] += f * sv;
  f = __builtin_amdgcn_cvt_pk_f32_fp8(v.y, false); a[2] += f * sv;
  f = __builtin_amdgcn_cvt_pk_f32_fp8(v.y, true);  a[3] += f * sv;
  f = __builtin_amdgcn_cvt_pk_f32_fp8(v.z, false); a[4] += f * sv;
  f = __builtin_amdgcn_cvt_pk_f32_fp8(v.z, true);  a[5] += f * sv;
  f = __builtin_amdgcn_cvt_pk_f32_fp8(v.w, false); a[6] += f * sv;
  f = __builtin_amdgcn_cvt_pk_f32_fp8(v.w, true);  a[7] += f * sv;
}

__global__ __launch_bounds__(256) void agg_fp8(const u8* __restrict__ H8,
                                               const float* __restrict__ sc,
                                               u16* __restrict__ Out,
                                               const int* __restrict__ rs,
                                               const u16* __restrict__ csr, int n) {
  int w = (blockIdx.x * 256 + threadIdx.x) >> 6;
  int lane = threadIdx.x & 63;
  if (w >= n) return;
  int beg = rs[w], end = rs[w + 1];
  const int halfe = lane >> 5;
  const int lsub = lane & 31;
  const int shalf = lsub >> 4;
  f32x2 acc[8];
#pragma unroll
  for (int i = 0; i < 8; ++i) acc[i] = (f32x2){0.f, 0.f};

  int e = beg;
  for (; e + 8 <= end; e += 8) {
    int si[4];
#pragma unroll
    for (int u = 0; u < 4; ++u) si[u] = csr[e + 2 * u + halfe];
    uint4 v[4];
#pragma unroll
    for (int u = 0; u < 4; ++u)
      v[u] = *(const uint4*)(H8 + (size_t)si[u] * 512 + lsub * 16);
    float cs[4];
#pragma unroll
    for (int u = 0; u < 4; ++u) cs[u] = sc[si[u] * 2 + shalf];
#pragma unroll
    for (int u = 0; u < 4; ++u) accp(acc, v[u], cs[u]);
  }
  if (e < end) {
#pragma unroll
    for (int u = 0; u < 4; ++u) {
      int ei = e + 2 * u + halfe;
      int ec = min(ei, end - 1);
      int s0 = csr[ec];
      uint4 v = *(const uint4*)(H8 + (size_t)s0 * 512 + lsub * 16);
      float c = (ei < end) ? sc[s0 * 2 + shalf] : 0.f;
      accp(acc, v, c);
    }
  }
#pragma unroll
  for (int i = 0; i < 8; ++i) {
    acc[i].x += __shfl_xor(acc[i].x, 32);
    acc[i].y += __shfl_xor(acc[i].y, 32);
  }
  uint4 o;
  if (halfe == 0) {
    o.x = pack2(acc[0].x, acc[0].y);
    o.y = pack2(acc[1].x, acc[1].y);
    o.z = pack2(acc[2].x, acc[2].y);
    o.w = pack2(acc[3].x, acc[3].y);
  } else {
    o.x = pack2(acc[4].x, acc[4].y);
    o.y = pack2(acc[5].x, acc[5].y);
    o.z = pack2(acc[6].x, acc[6].y);
    o.w = pack2(acc[7].x, acc[7].y);
  }
  *(uint4*)(Out + (size_t)w * 512 + lsub * 16 + halfe * 8) = o;
}

// ---------------- GEMM bf16 128x256 (layer 1, K=256) ----------------

__global__ __launch_bounds__(512, 4) void gemm256(
    const u16* __restrict__ A1, int lda1, int Ktot, const u16* __restrict__ Bt,
    const float* __restrict__ bias, int relu,
    u16* __restrict__ out_bf, int ldob, float* __restrict__ out_f32, int ldof,
    u8* __restrict__ out_fp8, float* __restrict__ out_sc, int M) {
  __shared__ u16 lA[3][128 * 32];
  __shared__ u16 lB[3][256 * 32];
  __shared__ u32 smaxu[128];
  const int tid = threadIdx.x;
  const int lane = tid & 63;
  const int wv = tid >> 6;
  const int wm = (wv >> 2) * 64;
  const int wn = (wv & 3) * 64;
  const int n0 = blockIdx.x * 256;
  const int m0 = blockIdx.y * 128;
  const int r15 = lane & 15;
  const int quad = lane >> 4;

  if (tid < 128) smaxu[tid] = 0;

  const int arow = tid >> 2;
  const int akc = ((tid & 3) ^ ((tid >> 3) & 3)) * 8;

  auto stage = [&](int kk, int b) {
    g2l16(A1 + (size_t)(m0 + arow) * lda1 + kk + akc, &lA[b][tid * 8]);
#pragma unroll
    for (int i = 0; i < 2; ++i) {
      int li = tid + i * 512;
      int kc = ((li & 3) ^ ((li >> 3) & 3)) * 8;
      g2l16(Bt + (size_t)(n0 + (li >> 2)) * Ktot + (kk + kc), &lB[b][li * 8]);
    }
  };

  f32x4 acc[4][4];
#pragma unroll
  for (int i = 0; i < 4; ++i)
#pragma unroll
    for (int j = 0; j < 4; ++j) acc[i][j] = (f32x4){0.f, 0.f, 0.f, 0.f};

  const int ntk = Ktot >> 5;
  stage(0, 0);
  stage(32, 1);
  for (int t = 0; t < ntk; ++t) {
    const int cur = t % 3;
    __builtin_amdgcn_s_barrier();
    if (t + 2 < ntk) stage((t + 2) * 32, (t + 2) % 3);
    if (t + 2 < ntk)      asm volatile("s_waitcnt vmcnt(6)" ::: "memory");
    else if (t + 1 < ntk) asm volatile("s_waitcnt vmcnt(3)" ::: "memory");
    else                  asm volatile("s_waitcnt vmcnt(0)" ::: "memory");
    __builtin_amdgcn_s_barrier();
    __builtin_amdgcn_sched_barrier(0);
    frag8 af[4], bfr[4];
#pragma unroll
    for (int mt = 0; mt < 4; ++mt) {
      int s = (wm + mt * 16 + r15) * 4 + quad;
      af[mt] = *(const frag8*)&lA[cur][swz(s) * 8];
    }
#pragma unroll
    for (int nt = 0; nt < 4; ++nt) {
      int s = (wn + nt * 16 + r15) * 4 + quad;
      bfr[nt] = *(const frag8*)&lB[cur][swz(s) * 8];
    }
#pragma unroll
    for (int mt = 0; mt < 4; ++mt)
#pragma unroll
      for (int nt = 0; nt < 4; ++nt)
        acc[mt][nt] =
            __builtin_amdgcn_mfma_f32_16x16x32_bf16(af[mt], bfr[nt], acc[mt][nt], 0, 0, 0);
  }
  __syncthreads();

#pragma unroll
  for (int mt = 0; mt < 4; ++mt) {
#pragma unroll
    for (int r = 0; r < 4; ++r) {
      float rm = 0.f;
#pragma unroll
      for (int nt = 0; nt < 4; ++nt) {
        int c = n0 + wn + nt * 16 + r15;
        float v = acc[mt][nt][r] + bias[c];
        if (relu) v = fmaxf(v, 0.f);
        acc[mt][nt][r] = v;
        rm = fmaxf(rm, v);
      }
      if (out_fp8) {
        rm = fmaxf(rm, __shfl_xor(rm, 1));
        rm = fmaxf(rm, __shfl_xor(rm, 2));
        rm = fmaxf(rm, __shfl_xor(rm, 4));
        rm = fmaxf(rm, __shfl_xor(rm, 8));
        if (r15 == 0) atomicMax(&smaxu[wm + mt * 16 + quad * 4 + r], __float_as_uint(rm));
      }
    }
  }
  if (out_fp8) __syncthreads();

#pragma unroll
  for (int mt = 0; mt < 4; ++mt) {
    int rloc = wm + mt * 16 + quad * 4;
#pragma unroll
    for (int r = 0; r < 4; ++r) {
      int row = m0 + rloc + r;
      if (row < M) {
        float inv = 0.f;
        if (out_fp8) {
          float s = __uint_as_float(smaxu[rloc + r]);
          inv = (s > 0.f) ? 448.f / s : 0.f;
          if (r15 == 0 && wn == 0)
            out_sc[row * 2 + (n0 >> 8)] = (s > 0.f) ? s / 448.f : 1.0f;
        }
#pragma unroll
        for (int nt = 0; nt < 4; ++nt) {
          int c = n0 + wn + nt * 16 + r15;
          float v = acc[mt][nt][r];
          if (out_f32) out_f32[(size_t)row * ldof + c] = v;
          if (out_bf) out_bf[(size_t)row * ldob + c] = f2bf(v);
        }
        if (out_fp8) {
          u32 u01 = (u32)__builtin_amdgcn_cvt_pk_fp8_f32(acc[mt][0][r] * inv,
                                                         acc[mt][1][r] * inv, 0, false);
          u32 u23 = (u32)__builtin_amdgcn_cvt_pk_fp8_f32(acc[mt][2][r] * inv,
                                                         acc[mt][3][r] * inv, 0, false);
          size_t rb = (size_t)row * 512 + n0 + wn + r15;
          out_fp8[rb] = (u8)(u01 & 0xff);
          out_fp8[rb + 16] = (u8)((u01 >> 8) & 0xff);
          out_fp8[rb + 32] = (u8)(u23 & 0xff);
          out_fp8[rb + 48] = (u8)((u23 >> 8) & 0xff);
        }
      }
    }
  }
}

// ------- HYBRID GEMM 128x256 (layers 2/3, K=1024 = 512 fp8 + 512 bf16) ----
// Steps 0-7 (fp8, BK=64): A2 = h fp8 (per row,half scales sA2), B = W_root
// fp8 (per-col sB). Rescale acc at t=4 (s0->s1) and t=8 (x s1*sB[c] -> true
// units). Steps 8-23 (bf16, BK=32): A1 = agg bf16, B = W_rel bf16.

__global__ __launch_bounds__(512, 4) void gemmh(
    const u16* __restrict__ A1, const u8* __restrict__ A2,
    const float* __restrict__ sA2, const u16* __restrict__ Bt1,
    const u8* __restrict__ Bt2, const float* __restrict__ sB,
    const float* __restrict__ bias,
    u16* __restrict__ out_bf, int ldob, float* __restrict__ out_f32, int ldof,
    u8* __restrict__ out_fp8, float* __restrict__ out_sc, int M) {
  __shared__ u8 lA[3][128 * 64];
  __shared__ u8 lB[3][256 * 64];
  __shared__ u32 smaxu[128];
  const int tid = threadIdx.x;
  const int lane = tid & 63;
  const int wv = tid >> 6;
  const int wm = (wv >> 2) * 64;
  const int wn = (wv & 3) * 64;
  const int n0 = blockIdx.x * 256;
  const int m0 = blockIdx.y * 128;
  const int r15 = lane & 15;
  const int quad = lane >> 4;

  if (tid < 128) smaxu[tid] = 0;

  const int arow = tid >> 2;
  const int achk = (tid & 3) ^ ((tid >> 3) & 3);

  // ts 0..7: fp8 (A2/Bt2, 64B/row-step); ts 8..23: bf16 (A1/Bt1, 32 elems).
  auto stage = [&](int ts, int b) {
    if (ts < 8) {
      int kk = ts * 64;
      g2l16(A2 + (size_t)(m0 + arow) * 512 + kk + achk * 16, &lA[b][tid * 16]);
#pragma unroll
      for (int i = 0; i < 2; ++i) {
        int li = tid + i * 512;
        int chk = (li & 3) ^ ((li >> 3) & 3);
        g2l16(Bt2 + (size_t)(n0 + (li >> 2)) * 512 + kk + chk * 16, &lB[b][li * 16]);
      }
    } else {
      int kk = (ts - 8) * 32;
      g2l16(A1 + (size_t)(m0 + arow) * 512 + kk + achk * 8, &lA[b][tid * 16]);
#pragma unroll
      for (int i = 0; i < 2; ++i) {
        int li = tid + i * 512;
        int chk = (li & 3) ^ ((li >> 3) & 3);
        g2l16(Bt1 + (size_t)(n0 + (li >> 2)) * 512 + kk + chk * 8, &lB[b][li * 16]);
      }
    }
  };

  f32x4 acc[4][4];
#pragma unroll
  for (int i = 0; i < 4; ++i)
#pragma unroll
    for (int j = 0; j < 4; ++j) acc[i][j] = (f32x4){0.f, 0.f, 0.f, 0.f};

  const int ntk = 24;
  stage(0, 0);
  stage(1, 1);
  for (int t = 0; t < ntk; ++t) {
    const int cur = t % 3;
    __builtin_amdgcn_s_barrier();
    if (t + 2 < ntk) stage(t + 2, (t + 2) % 3);
    if (t + 2 < ntk)      asm volatile("s_waitcnt vmcnt(6)" ::: "memory");
    else if (t + 1 < ntk) asm volatile("s_waitcnt vmcnt(3)" ::: "memory");
    else                  asm volatile("s_waitcnt vmcnt(0)" ::: "memory");
    __builtin_amdgcn_s_barrier();
    __builtin_amdgcn_sched_barrier(0);
    if (t == 4) {  // h half0 units -> half1 units
#pragma unroll
      for (int mt = 0; mt < 4; ++mt)
#pragma unroll
        for (int r = 0; r < 4; ++r) {
          int row = m0 + wm + mt * 16 + quad * 4 + r;
          float ra = sA2[row * 2] / sA2[row * 2 + 1];
#pragma unroll
          for (int nt = 0; nt < 4; ++nt) acc[mt][nt][r] *= ra;
        }
    }
    if (t == 8) {  // fp8 region done: convert to true units (s1 * sB[c])
#pragma unroll
      for (int mt = 0; mt < 4; ++mt)
#pragma unroll
        for (int r = 0; r < 4; ++r) {
          int row = m0 + wm + mt * 16 + quad * 4 + r;
          float s1 = sA2[row * 2 + 1];
#pragma unroll
          for (int nt = 0; nt < 4; ++nt) {
            int c = n0 + wn + nt * 16 + r15;
            acc[mt][nt][r] *= s1 * sB[c];
          }
        }
    }
    if (t < 8) {
#pragma unroll
      for (int ks = 0; ks < 2; ++ks) {
        i64 af[4], bfr[4];
#pragma unroll
        for (int mt = 0; mt < 4; ++mt) {
          int s = (wm + mt * 16 + r15) * 4 + ks * 2 + (quad >> 1);
          af[mt] = *(const i64*)&lA[cur][swz(s) * 16 + (quad & 1) * 8];
        }
#pragma unroll
        for (int nt = 0; nt < 4; ++nt) {
          int s = (wn + nt * 16 + r15) * 4 + ks * 2 + (quad >> 1);
          bfr[nt] = *(const i64*)&lB[cur][swz(s) * 16 + (quad & 1) * 8];
        }
#pragma unroll
        for (int mt = 0; mt < 4; ++mt)
#pragma unroll
          for (int nt = 0; nt < 4; ++nt)
            acc[mt][nt] = __builtin_amdgcn_mfma_f32_16x16x32_fp8_fp8(af[mt], bfr[nt],
                                                                     acc[mt][nt], 0, 0, 0);
      }
    } else {
      frag8 af[4], bfr[4];
#pragma unroll
      for (int mt = 0; mt < 4; ++mt) {
        int s = (wm + mt * 16 + r15) * 4 + quad;
        af[mt] = *(const frag8*)&lA[cur][swz(s) * 16];
      }
#pragma unroll
      for (int nt = 0; nt < 4; ++nt) {
        int s = (wn + nt * 16 + r15) * 4 + quad;
        bfr[nt] = *(const frag8*)&lB[cur][swz(s) * 16];
      }
#pragma unroll
      for (int mt = 0; mt < 4; ++mt)
#pragma unroll
        for (int nt = 0; nt < 4; ++nt)
          acc[mt][nt] =
              __builtin_amdgcn_mfma_f32_16x16x32_bf16(af[mt], bfr[nt], acc[mt][nt], 0, 0, 0);
    }
  }
  __syncthreads();

#pragma unroll
  for (int mt = 0; mt < 4; ++mt) {
#pragma unroll
    for (int r = 0; r < 4; ++r) {
      float rm = 0.f;
#pragma unroll
      for (int nt = 0; nt < 4; ++nt) {
        int c = n0 + wn + nt * 16 + r15;
        float v = acc[mt][nt][r] + bias[c];
        v = fmaxf(v, 0.f);  // layers 2/3 both relu
        acc[mt][nt][r] = v;
        rm = fmaxf(rm, v);
      }
      if (out_fp8) {
        rm = fmaxf(rm, __shfl_xor(rm, 1));
        rm = fmaxf(rm, __shfl_xor(rm, 2));
        rm = fmaxf(rm, __shfl_xor(rm, 4));
        rm = fmaxf(rm, __shfl_xor(rm, 8));
        if (r15 == 0) atomicMax(&smaxu[wm + mt * 16 + quad * 4 + r], __float_as_uint(rm));
      }
    }
  }
  if (out_fp8) __syncthreads();

#pragma unroll
  for (int mt = 0; mt < 4; ++mt) {
    int rloc = wm + mt * 16 + quad * 4;
#pragma unroll
    for (int r = 0; r < 4; ++r) {
      int row = m0 + rloc + r;
      if (row < M) {
        float inv = 0.f;
        if (out_fp8) {
          float s = __uint_as_float(smaxu[rloc + r]);
          inv = (s > 0.f) ? 448.f / s : 0.f;
          if (r15 == 0 && wn == 0)
            out_sc[row * 2 + (n0 >> 8)] = (s > 0.f) ? s / 448.f : 1.0f;
        }
#pragma unroll
        for (int nt = 0; nt < 4; ++nt) {
          int c = n0 + wn + nt * 16 + r15;
          float v = acc[mt][nt][r];
          if (out_f32) out_f32[(size_t)row * ldof + c] = v;
          if (out_bf) out_bf[(size_t)row * ldob + c] = f2bf(v);
        }
        if (out_fp8) {
          u32 u01 = (u32)__builtin_amdgcn_cvt_pk_fp8_f32(acc[mt][0][r] * inv,
                                                         acc[mt][1][r] * inv, 0, false);
          u32 u23 = (u32)__builtin_amdgcn_cvt_pk_fp8_f32(acc[mt][2][r] * inv,
                                                         acc[mt][3][r] * inv, 0, false);
          size_t rb = (size_t)row * 512 + n0 + wn + r15;
          out_fp8[rb] = (u8)(u01 & 0xff);
          out_fp8[rb + 16] = (u8)((u01 >> 8) & 0xff);
          out_fp8[rb + 32] = (u8)(u23 & 0xff);
          out_fp8[rb + 48] = (u8)((u23 >> 8) & 0xff);
        }
      }
    }
  }
}

// ---------------- head GEMM 128x64 tile, 256 threads ----------------

__global__ __launch_bounds__(256) void gemm64(
    const u16* __restrict__ A1, int lda1, int Ktot, const u16* __restrict__ Bt,
    const float* __restrict__ bias, float* __restrict__ out_f32, int ldof, int M) {
  __shared__ u16 lA[3][128 * 32];
  __shared__ u16 lB[3][64 * 32];
  const int tid = threadIdx.x;
  const int lane = tid & 63;
  const int wv = tid >> 6;
  const int wm = (wv >> 1) * 64;
  const int wn = (wv & 1) * 32;
  const int m0 = blockIdx.x * 128;
  const int r15 = lane & 15;
  const int quad = lane >> 4;

  auto stage = [&](int kk, int b) {
#pragma unroll
    for (int i = 0; i < 2; ++i) {
      int li = tid + i * 256;
      int kc = ((li & 3) ^ ((li >> 3) & 3)) * 8;
      g2l16(A1 + (size_t)(m0 + (li >> 2)) * lda1 + kk + kc, &lA[b][li * 8]);
    }
    {
      int kc = ((tid & 3) ^ ((tid >> 3) & 3)) * 8;
      g2l16(Bt + (size_t)(tid >> 2) * Ktot + (kk + kc), &lB[b][tid * 8]);
    }
  };

  f32x4 acc[4][2];
#pragma unroll
  for (int i = 0; i < 4; ++i)
#pragma unroll
    for (int j = 0; j < 2; ++j) acc[i][j] = (f32x4){0.f, 0.f, 0.f, 0.f};

  const int ntk = Ktot >> 5;
  stage(0, 0);
  stage(32, 1);
  for (int t = 0; t < ntk; ++t) {
    const int cur = t % 3;
    __builtin_amdgcn_s_barrier();
    if (t + 2 < ntk) stage((t + 2) * 32, (t + 2) % 3);
    if (t + 2 < ntk)      asm volatile("s_waitcnt vmcnt(6)" ::: "memory");
    else if (t + 1 < ntk) asm volatile("s_waitcnt vmcnt(3)" ::: "memory");
    else                  asm volatile("s_waitcnt vmcnt(0)" ::: "memory");
    __builtin_amdgcn_s_barrier();
    __builtin_amdgcn_sched_barrier(0);
    frag8 af[4], bfr[2];
#pragma unroll
    for (int mt = 0; mt < 4; ++mt) {
      int s = (wm + mt * 16 + r15) * 4 + quad;
      af[mt] = *(const frag8*)&lA[cur][swz(s) * 8];
    }
#pragma unroll
    for (int nt = 0; nt < 2; ++nt) {
      int s = (wn + nt * 16 + r15) * 4 + quad;
      bfr[nt] = *(const frag8*)&lB[cur][swz(s) * 8];
    }
#pragma unroll
    for (int mt = 0; mt < 4; ++mt)
#pragma unroll
      for (int nt = 0; nt < 2; ++nt)
        acc[mt][nt] =
            __builtin_amdgcn_mfma_f32_16x16x32_bf16(af[mt], bfr[nt], acc[mt][nt], 0, 0, 0);
  }

#pragma unroll
  for (int mt = 0; mt < 4; ++mt) {
    int rbase = m0 + wm + mt * 16 + quad * 4;
#pragma unroll
    for (int r = 0; r < 4; ++r) {
      int row = rbase + r;
      if (row < M) {
#pragma unroll
        for (int nt = 0; nt < 2; ++nt) {
          int c = wn + nt * 16 + r15;
          out_f32[(size_t)row * ldof + c] = acc[mt][nt][r] + bias[c];
        }
      }
    }
  }
}

// ---------------- launch ----------------

extern "C" void kernel_launch(void* const* d_in, const int* in_sizes, int n_in, void* d_out,
                              int out_size, void* d_ws, size_t ws_size, hipStream_t stream) {
  const float* x = (const float*)d_in[0];
  const float* W1r = (const float*)d_in[1];
  const float* b1 = (const float*)d_in[2];
  const float* W1o = (const float*)d_in[3];
  const float* W2r = (const float*)d_in[4];
  const float* b2 = (const float*)d_in[5];
  const float* W2o = (const float*)d_in[6];
  const float* W3r = (const float*)d_in[7];
  const float* b3 = (const float*)d_in[8];
  const float* W3o = (const float*)d_in[9];
  const float* Wl = (const float*)d_in[10];
  const float* bl = (const float*)d_in[11];
  const int* src = (const int*)d_in[12];
  const int* dst = src + NE;

  size_t off = 0;
  char* ws = (char*)d_ws;
  auto take = [&](size_t bytes) -> void* {
    void* p = ws + off;
    off = (off + bytes + 255) & ~(size_t)255;
    return p;
  };
  u16* h13 = (u16*)take((size_t)MPAD * 512 * 2);   // h3 bf16 (head input)
  u16* h2b = (u16*)take((size_t)MPAD * 512 * 2);   // carved: hfp8_b + scb_b
  u16* aggB = (u16*)take((size_t)MPAD * 512 * 2);  // layer1 aggx[.][256] / agg bf16 [.][512]
  u16* aggx = aggB;
  u8* hfp8a = (u8*)take((size_t)MPAD * 512);       // h1 fp8
  float* scba = (float*)take((size_t)MPAD * 2 * 4);
  u8* hfp8b = (u8*)h2b;                                // h2 fp8
  float* scbb = (float*)((char*)h2b + (size_t)MPAD * 512);
  u16* wt1 = (u16*)take((size_t)512 * 256 * 2);
  u16* wt2 = (u16*)take((size_t)512 * 512 * 2);    // W2_rel bf16 [n][512]
  u16* wt3 = (u16*)take((size_t)512 * 512 * 2);    // W3_rel bf16
  u8* wtf2 = (u8*)take((size_t)512 * 512);         // W2_root fp8 [n][512]
  float* sB2 = (float*)take(512 * 4);
  u8* wtf3 = (u8*)take((size_t)512 * 512);         // W3_root fp8
  float* sB3 = (float*)take(512 * 4);
  u16* wtl = (u16*)take((size_t)64 * 512 * 2);
  u32* region = (u32*)take((size_t)NBKT * CAP * 4);
  int* gcur = (int*)take(128 * 4);
  int* bbase = (int*)take(128 * 4);
  int* rs = (int*)take((size_t)(NN + 1) * 4);
  u16* csr = (u16*)take((size_t)NE * 2);

  float* out_logits = (float*)d_out;
  float* out_embed = out_logits + (size_t)NN * 64;

  // binned CSR build
  zero_i32<<<1, 128, 0, stream>>>(gcur, NBKT);
  p1bin<<<(NE + 2047) / 2048, 256, 0, stream>>>(src, dst, gcur, region, NE);
  scan98<<<1, 64, 0, stream>>>(gcur, bbase, rs);
  p2build<<<NBKT, 256, 0, stream>>>(region, gcur, bbase, rs, csr);

  // conversions
  f2bf_x<<<(NN * 32 + 255) / 256, 256, 0, stream>>>((const float4*)x, aggx, NN * 32);
  wtrans<<<(512 * 256 + 255) / 256, 256, 0, stream>>>(W1r, 128, W1o, 128, 512, wt1);
  wtrans<<<(512 * 512 + 255) / 256, 256, 0, stream>>>(W2r, 512, W2r, 0, 512, wt2);
  wtrans<<<(512 * 512 + 255) / 256, 256, 0, stream>>>(W3r, 512, W3r, 0, 512, wt3);
  wtransf8<<<128, 256, 0, stream>>>(W2o, 512, wtf2, sB2);
  wtransf8<<<128, 256, 0, stream>>>(W3o, 512, wtf3, sB3);
  wtrans<<<(64 * 512 + 255) / 256, 256, 0, stream>>>(Wl, 512, Wl, 0, 64, wtl);

  // layer 1 (bf16): agg(x); h1 = relu([agg|x] @ W1 + b1) -> fp8 only
  agg_bf128<<<(NN + 3) / 4, 256, 0, stream>>>(aggx + 128, 256, aggx, 256, rs, csr, NN);
  gemm256<<<dim3(2, GRID_M), 512, 0, stream>>>(aggx, 256, 256, wt1, b1, 1,
                                               (u16*)nullptr, 0, (float*)nullptr, 0,
                                               hfp8a, scba, NN);
  // layer 2: agg(h1 fp8) -> bf16; h2 = relu(agg@W2rel + h1@W2root + b2) -> fp8
  agg_fp8<<<(NN + 3) / 4, 256, 0, stream>>>(hfp8a, scba, aggB, rs, csr, NN);
  gemmh<<<dim3(2, GRID_M), 512, 0, stream>>>(aggB, hfp8a, scba, wt2, wtf2, sB2, b2,
                                             (u16*)nullptr, 0, (float*)nullptr, 0,
                                             hfp8b, scbb, NN);
  // layer 3: agg(h2 fp8); h3 -> bf16 + f32 embed
  agg_fp8<<<(NN + 3) / 4, 256, 0, stream>>>(hfp8b, scbb, aggB, rs, csr, NN);
  gemmh<<<dim3(2, GRID_M), 512, 0, stream>>>(aggB, hfp8b, scbb, wt3, wtf3, sB3, b3,
                                             h13, 512, out_embed, 512,
                                             (u8*)nullptr, (float*)nullptr, NN);
  // head
  gemm64<<<GRID_M, 256, 0, stream>>>(h13, 512, 512, wtl, bl, out_logits, 64, NN);
}

// Round 10
// 782.131 us; speedup vs baseline: 2.2423x; 2.2423x over previous
//
#include <hip/hip_runtime.h>

// GNN1: 3x GraphConv(add) + linear head on MI355X.
// R6 CSR; R7 agg 109us (mem wall); R8-R10 sliced agg LOSS; R11 neutral;
// R12 chunk-major LOSS; R13 swizzle+ring neutral (733us); R14 full-fp8
// FAILED accuracy; R15 hybrid PASSED (absmax 48!) but gemmh spilled:
// VGPR=64 cap + dual-dtype branch-in-loop -> 1.39GB scratch writes, 614us.
// R16: fix the spill: (a) split gemmh into two sequential pipelined loops
// (8 fp8 steps then 16 bf16 steps), one dtype per loop; (b)
// __launch_bounds__(512,2): LDS already caps at 2 blocks/CU so the VGPR
// cap rises to 256 free; (c) rescales at loop boundaries.

typedef unsigned short u16;
typedef unsigned int u32;
typedef unsigned char u8;
typedef long i64;

#define NN 50000
#define NE 1600000
#define MPAD 50176
#define GRID_M ((NN + 127) / 128)  // 391
#define NBKT 98
#define CAP 20480
#define STG 18432

using frag8 = __attribute__((ext_vector_type(8))) short;
using f32x4 = __attribute__((ext_vector_type(4))) float;
using f32x2 = __attribute__((ext_vector_type(2))) float;

__device__ __forceinline__ u16 f2bf(float f) {
  u32 u = __float_as_uint(f);
  u32 r = u + 0x7fffu + ((u >> 16) & 1u);
  return (u16)(r >> 16);
}
__device__ __forceinline__ float lo2f(u32 u) { return __uint_as_float(u << 16); }
__device__ __forceinline__ float hi2f(u32 u) { return __uint_as_float(u & 0xffff0000u); }
__device__ __forceinline__ u32 pack2(float a, float b) {
  return (u32)f2bf(a) | ((u32)f2bf(b) << 16);
}

__device__ __forceinline__ void g2l16(const void* g, void* l) {
  __builtin_amdgcn_global_load_lds((const __attribute__((address_space(1))) void*)g,
                                   (__attribute__((address_space(3))) void*)l, 16, 0, 0);
}

// 16B-slot XOR swizzle (involution): chunk bits[1:0] ^= bits[4:3].
__device__ __forceinline__ int swz(int s) { return s ^ ((s >> 3) & 3); }

// ---------------- binned CSR build ----------------

__global__ void zero_i32(int* p, int n) {
  int i = blockIdx.x * 256 + threadIdx.x;
  if (i < n) p[i] = 0;
}

__global__ __launch_bounds__(256) void p1bin(const int* __restrict__ src,
                                             const int* __restrict__ dst,
                                             int* __restrict__ gcur,
                                             u32* __restrict__ region, int ne) {
  __shared__ u32 lbuf[NBKT * 64];
  __shared__ int lcnt[NBKT];
  __shared__ int gbase[NBKT];
  const int tid = threadIdx.x;
  if (tid < NBKT) lcnt[tid] = 0;
  __syncthreads();
  const int base = blockIdx.x * 2048;
#pragma unroll
  for (int j = 0; j < 8; ++j) {
    int i = base + j * 256 + tid;
    if (i < ne) {
      int d = dst[i];
      int s = src[i];
      int b = d >> 9;
      u32 entry = ((u32)(d & 511) << 16) | (u32)s;
      int slot = atomicAdd(&lcnt[b], 1);
      if (slot < 64) lbuf[b * 64 + slot] = entry;
      else {
        int g = atomicAdd(&gcur[b], 1);
        region[(size_t)b * CAP + g] = entry;
      }
    }
  }
  __syncthreads();
  if (tid < NBKT) {
    int c = min(lcnt[tid], 64);
    gbase[tid] = atomicAdd(&gcur[tid], c);
  }
  __syncthreads();
  const int wv = tid >> 6, lane = tid & 63;
  for (int b = wv; b < NBKT; b += 4) {
    int c = min(lcnt[b], 64);
    int gb = gbase[b];
    for (int s2 = lane; s2 < c; s2 += 64)
      region[(size_t)b * CAP + gb + s2] = lbuf[b * 64 + s2];
  }
}

__global__ void scan98(const int* __restrict__ gcur, int* __restrict__ bbase,
                       int* __restrict__ rs) {
  if (threadIdx.x == 0) {
    int run = 0;
    for (int b = 0; b < NBKT; ++b) {
      bbase[b] = run;
      run += gcur[b];
    }
    bbase[NBKT] = run;
    rs[NN] = run;
  }
}

__global__ __launch_bounds__(256) void p2build(const u32* __restrict__ region,
                                               const int* __restrict__ gcnt,
                                               const int* __restrict__ bbase,
                                               int* __restrict__ rs,
                                               u16* __restrict__ csr) {
  __shared__ int cnt[512];
  __shared__ int off[512];
  __shared__ int sh[256];
  __shared__ u16 stg[STG];
  const int b = blockIdx.x, tid = threadIdx.x;
  const int n0 = b * 512;
  const int nnb = min(512, NN - n0);
  const int ec = gcnt[b];
  const int gb = bbase[b];
  const u32* __restrict__ reg = region + (size_t)b * CAP;
  cnt[tid] = 0;
  cnt[tid + 256] = 0;
  __syncthreads();
  for (int i = tid; i < ec; i += 256) atomicAdd(&cnt[reg[i] >> 16], 1);
  __syncthreads();
  int c0 = cnt[2 * tid], c1 = cnt[2 * tid + 1];
  int s = c0 + c1;
  sh[tid] = s;
  __syncthreads();
  for (int o = 1; o < 256; o <<= 1) {
    int t2 = (tid >= o) ? sh[tid - o] : 0;
    __syncthreads();
    sh[tid] += t2;
    __syncthreads();
  }
  int base0 = sh[tid] - s;
  off[2 * tid] = base0;
  off[2 * tid + 1] = base0 + c0;
  __syncthreads();
  if (2 * tid < nnb) rs[n0 + 2 * tid] = gb + off[2 * tid];
  if (2 * tid + 1 < nnb) rs[n0 + 2 * tid + 1] = gb + off[2 * tid + 1];
  cnt[2 * tid] = off[2 * tid];
  cnt[2 * tid + 1] = off[2 * tid + 1];
  __syncthreads();
  for (int i = tid; i < ec; i += 256) {
    u32 e = reg[i];
    int slot = atomicAdd(&cnt[e >> 16], 1);
    u16 sv = (u16)(e & 0xffff);
    if (slot < STG) stg[slot] = sv;
    else csr[gb + slot] = sv;
  }
  __syncthreads();
  for (int i = tid; i < ec && i < STG; i += 256) csr[gb + i] = stg[i];
}

// ---------------- dtype conversion ----------------

__global__ void f2bf_x(const float4* __restrict__ in, u16* __restrict__ out, int n4) {
  int i = blockIdx.x * 256 + threadIdx.x;
  if (i < n4) {
    float4 v = in[i];
    int node = i >> 5;
    int w = i & 31;
    uint2 o;
    o.x = pack2(v.x, v.y);
    o.y = pack2(v.z, v.w);
    *(uint2*)(out + (size_t)node * 256 + 128 + w * 4) = o;
  }
}

__global__ void wtrans(const float* __restrict__ Wa, int Ka, const float* __restrict__ Wb,
                       int Kb, int N, u16* __restrict__ out) {
  int idx = blockIdx.x * 256 + threadIdx.x;
  int Kt = Ka + Kb;
  if (idx >= N * Kt) return;
  int n = idx / Kt;
  int k = idx - n * Kt;
  float v = (k < Ka) ? Wa[(size_t)k * N + n] : Wb[(size_t)(k - Ka) * N + n];
  out[idx] = f2bf(v);
}

// W [512 x N] f32 -> fp8 out[n][512] with per-col scale. One wave per col.
__global__ __launch_bounds__(256) void wtransf8(const float* __restrict__ W, int N,
                                                u8* __restrict__ out,
                                                float* __restrict__ sB) {
  int n = blockIdx.x * 4 + (threadIdx.x >> 6);
  int lane = threadIdx.x & 63;
  if (n >= N) return;
  float v[8];
  float m = 0.f;
#pragma unroll
  for (int j = 0; j < 8; ++j) {
    float x = W[(size_t)(lane * 8 + j) * N + n];
    v[j] = x;
    m = fmaxf(m, fabsf(x));
  }
#pragma unroll
  for (int o = 1; o < 64; o <<= 1) m = fmaxf(m, __shfl_xor(m, o));
  float inv = (m > 0.f) ? 448.f / m : 0.f;
  uint2 o2;
  u32 lo0 = (u32)__builtin_amdgcn_cvt_pk_fp8_f32(v[0] * inv, v[1] * inv, 0, false);
  u32 hi0 = (u32)__builtin_amdgcn_cvt_pk_fp8_f32(v[2] * inv, v[3] * inv, 0, false);
  u32 lo1 = (u32)__builtin_amdgcn_cvt_pk_fp8_f32(v[4] * inv, v[5] * inv, 0, false);
  u32 hi1 = (u32)__builtin_amdgcn_cvt_pk_fp8_f32(v[6] * inv, v[7] * inv, 0, false);
  o2.x = (lo0 & 0xffffu) | (hi0 << 16);
  o2.y = (lo1 & 0xffffu) | (hi1 << 16);
  *(uint2*)(out + (size_t)n * 512 + lane * 8) = o2;
  if (lane == 0) sB[n] = (m > 0.f) ? m / 448.f : 1.0f;
}

// ---------------- layer-1 aggregation: bf16, 128 dims ----------------

__device__ __forceinline__ void accb(f32x2* a, uint4 v, float s) {
  f32x2 sv = (f32x2){s, s};
  f32x2 f;
  f.x = lo2f(v.x); f.y = hi2f(v.x); a[0] += f * sv;
  f.x = lo2f(v.y); f.y = hi2f(v.y); a[1] += f * sv;
  f.x = lo2f(v.z); f.y = hi2f(v.z); a[2] += f * sv;
  f.x = lo2f(v.w); f.y = hi2f(v.w); a[3] += f * sv;
}

__global__ __launch_bounds__(256) void agg_bf128(const u16* __restrict__ H, int ldh,
                                                 u16* __restrict__ Out, int ldo,
                                                 const int* __restrict__ rs,
                                                 const u16* __restrict__ csr, int n) {
  int w = (blockIdx.x * 256 + threadIdx.x) >> 6;
  int lane = threadIdx.x & 63;
  if (w >= n) return;
  int beg = rs[w], end = rs[w + 1];
  const int q = lane >> 4;
  const int lsub = lane & 15;
  f32x2 acc[4];
#pragma unroll
  for (int i = 0; i < 4; ++i) acc[i] = (f32x2){0.f, 0.f};

  int e = beg;
  for (; e + 16 <= end; e += 16) {
    int si[4];
#pragma unroll
    for (int u = 0; u < 4; ++u) si[u] = csr[e + 4 * u + q];
    uint4 v[4];
#pragma unroll
    for (int u = 0; u < 4; ++u)
      v[u] = *(const uint4*)(H + (size_t)si[u] * ldh + lsub * 8);
#pragma unroll
    for (int u = 0; u < 4; ++u) accb(acc, v[u], 1.f);
  }
  if (e < end) {
#pragma unroll
    for (int u = 0; u < 4; ++u) {
      int ei = e + 4 * u + q;
      int ec = min(ei, end - 1);
      int s0 = csr[ec];
      uint4 v = *(const uint4*)(H + (size_t)s0 * ldh + lsub * 8);
      accb(acc, v, (ei < end) ? 1.f : 0.f);
    }
  }
#pragma unroll
  for (int i = 0; i < 4; ++i) {
    acc[i].x += __shfl_xor(acc[i].x, 16);
    acc[i].y += __shfl_xor(acc[i].y, 16);
    acc[i].x += __shfl_xor(acc[i].x, 32);
    acc[i].y += __shfl_xor(acc[i].y, 32);
  }
  if (lane < 32) {
    int qq = lane >> 4;
    uint2 o;
    o.x = pack2(acc[qq * 2].x, acc[qq * 2].y);
    o.y = pack2(acc[qq * 2 + 1].x, acc[qq * 2 + 1].y);
    *(uint2*)(Out + (size_t)w * ldo + (lane & 15) * 8 + qq * 4) = o;
  }
}

// ---------------- 512-dim aggregation: fp8 in -> bf16 out ----------------

__device__ __forceinline__ void accp(f32x2* a, uint4 v, float s) {
  f32x2 sv = (f32x2){s, s};
  f32x2 f;
  f = __builtin_amdgcn_cvt_pk_f32_fp8(v.x, false); a[0] += f * sv;
  f = __builtin_amdgcn_cvt_pk_f32_fp8(v.x, true);  a[1] += f * sv;
  f = __builtin_amdgcn_cvt_pk_f32_fp8(v.y, false); a[2] += f * sv;
  f = __builtin_amdgcn_cvt_pk_f32_fp8(v.y, true);  a[3] += f * sv;
  f = __builtin_amdgcn_cvt_pk_f32_fp8(v.z, false); a[4] += f * sv;
  f = __builtin_amdgcn_cvt_pk_f32_fp8(v.z, true);  a[5] += f * sv;
  f = __builtin_amdgcn_cvt_pk_f32_fp8(v.w, false); a[6] += f * sv;
  f = __builtin_amdgcn_cvt_pk_f32_fp8(v.w, true);  a[7] += f * sv;
}

__global__ __launch_bounds__(256) void agg_fp8(const u8* __restrict__ H8,
                                               const float* __restrict__ sc,
                                               u16* __restrict__ Out,
                                               const int* __restrict__ rs,
                                               const u16* __restrict__ csr, int n) {
  int w = (blockIdx.x * 256 + threadIdx.x) >> 6;
  int lane = threadIdx.x & 63;
  if (w >= n) return;
  int beg = rs[w], end = rs[w + 1];
  const int halfe = lane >> 5;
  const int lsub = lane & 31;
  const int shalf = lsub >> 4;
  f32x2 acc[8];
#pragma unroll
  for (int i = 0; i < 8; ++i) acc[i] = (f32x2){0.f, 0.f};

  int e = beg;
  for (; e + 8 <= end; e += 8) {
    int si[4];
#pragma unroll
    for (int u = 0; u < 4; ++u) si[u] = csr[e + 2 * u + halfe];
    uint4 v[4];
#pragma unroll
    for (int u = 0; u < 4; ++u)
      v[u] = *(const uint4*)(H8 + (size_t)si[u] * 512 + lsub * 16);
    float cs[4];
#pragma unroll
    for (int u = 0; u < 4; ++u) cs[u] = sc[si[u] * 2 + shalf];
#pragma unroll
    for (int u = 0; u < 4; ++u) accp(acc, v[u], cs[u]);
  }
  if (e < end) {
#pragma unroll
    for (int u = 0; u < 4; ++u) {
      int ei = e + 2 * u + halfe;
      int ec = min(ei, end - 1);
      int s0 = csr[ec];
      uint4 v = *(const uint4*)(H8 + (size_t)s0 * 512 + lsub * 16);
      float c = (ei < end) ? sc[s0 * 2 + shalf] : 0.f;
      accp(acc, v, c);
    }
  }
#pragma unroll
  for (int i = 0; i < 8; ++i) {
    acc[i].x += __shfl_xor(acc[i].x, 32);
    acc[i].y += __shfl_xor(acc[i].y, 32);
  }
  uint4 o;
  if (halfe == 0) {
    o.x = pack2(acc[0].x, acc[0].y);
    o.y = pack2(acc[1].x, acc[1].y);
    o.z = pack2(acc[2].x, acc[2].y);
    o.w = pack2(acc[3].x, acc[3].y);
  } else {
    o.x = pack2(acc[4].x, acc[4].y);
    o.y = pack2(acc[5].x, acc[5].y);
    o.z = pack2(acc[6].x, acc[6].y);
    o.w = pack2(acc[7].x, acc[7].y);
  }
  *(uint4*)(Out + (size_t)w * 512 + lsub * 16 + halfe * 8) = o;
}

// ---------------- GEMM bf16 128x256 (layer 1, K=256) ----------------

__global__ __launch_bounds__(512, 4) void gemm256(
    const u16* __restrict__ A1, int lda1, int Ktot, const u16* __restrict__ Bt,
    const float* __restrict__ bias, int relu,
    u16* __restrict__ out_bf, int ldob, float* __restrict__ out_f32, int ldof,
    u8* __restrict__ out_fp8, float* __restrict__ out_sc, int M) {
  __shared__ u16 lA[3][128 * 32];
  __shared__ u16 lB[3][256 * 32];
  __shared__ u32 smaxu[128];
  const int tid = threadIdx.x;
  const int lane = tid & 63;
  const int wv = tid >> 6;
  const int wm = (wv >> 2) * 64;
  const int wn = (wv & 3) * 64;
  const int n0 = blockIdx.x * 256;
  const int m0 = blockIdx.y * 128;
  const int r15 = lane & 15;
  const int quad = lane >> 4;

  if (tid < 128) smaxu[tid] = 0;

  const int arow = tid >> 2;
  const int akc = ((tid & 3) ^ ((tid >> 3) & 3)) * 8;

  auto stage = [&](int kk, int b) {
    g2l16(A1 + (size_t)(m0 + arow) * lda1 + kk + akc, &lA[b][tid * 8]);
#pragma unroll
    for (int i = 0; i < 2; ++i) {
      int li = tid + i * 512;
      int kc = ((li & 3) ^ ((li >> 3) & 3)) * 8;
      g2l16(Bt + (size_t)(n0 + (li >> 2)) * Ktot + (kk + kc), &lB[b][li * 8]);
    }
  };

  f32x4 acc[4][4];
#pragma unroll
  for (int i = 0; i < 4; ++i)
#pragma unroll
    for (int j = 0; j < 4; ++j) acc[i][j] = (f32x4){0.f, 0.f, 0.f, 0.f};

  const int ntk = Ktot >> 5;
  stage(0, 0);
  stage(32, 1);
  for (int t = 0; t < ntk; ++t) {
    const int cur = t % 3;
    __builtin_amdgcn_s_barrier();
    if (t + 2 < ntk) stage((t + 2) * 32, (t + 2) % 3);
    if (t + 2 < ntk)      asm volatile("s_waitcnt vmcnt(6)" ::: "memory");
    else if (t + 1 < ntk) asm volatile("s_waitcnt vmcnt(3)" ::: "memory");
    else                  asm volatile("s_waitcnt vmcnt(0)" ::: "memory");
    __builtin_amdgcn_s_barrier();
    __builtin_amdgcn_sched_barrier(0);
    frag8 af[4], bfr[4];
#pragma unroll
    for (int mt = 0; mt < 4; ++mt) {
      int s = (wm + mt * 16 + r15) * 4 + quad;
      af[mt] = *(const frag8*)&lA[cur][swz(s) * 8];
    }
#pragma unroll
    for (int nt = 0; nt < 4; ++nt) {
      int s = (wn + nt * 16 + r15) * 4 + quad;
      bfr[nt] = *(const frag8*)&lB[cur][swz(s) * 8];
    }
#pragma unroll
    for (int mt = 0; mt < 4; ++mt)
#pragma unroll
      for (int nt = 0; nt < 4; ++nt)
        acc[mt][nt] =
            __builtin_amdgcn_mfma_f32_16x16x32_bf16(af[mt], bfr[nt], acc[mt][nt], 0, 0, 0);
  }
  __syncthreads();

#pragma unroll
  for (int mt = 0; mt < 4; ++mt) {
#pragma unroll
    for (int r = 0; r < 4; ++r) {
      float rm = 0.f;
#pragma unroll
      for (int nt = 0; nt < 4; ++nt) {
        int c = n0 + wn + nt * 16 + r15;
        float v = acc[mt][nt][r] + bias[c];
        if (relu) v = fmaxf(v, 0.f);
        acc[mt][nt][r] = v;
        rm = fmaxf(rm, v);
      }
      if (out_fp8) {
        rm = fmaxf(rm, __shfl_xor(rm, 1));
        rm = fmaxf(rm, __shfl_xor(rm, 2));
        rm = fmaxf(rm, __shfl_xor(rm, 4));
        rm = fmaxf(rm, __shfl_xor(rm, 8));
        if (r15 == 0) atomicMax(&smaxu[wm + mt * 16 + quad * 4 + r], __float_as_uint(rm));
      }
    }
  }
  if (out_fp8) __syncthreads();

#pragma unroll
  for (int mt = 0; mt < 4; ++mt) {
    int rloc = wm + mt * 16 + quad * 4;
#pragma unroll
    for (int r = 0; r < 4; ++r) {
      int row = m0 + rloc + r;
      if (row < M) {
        float inv = 0.f;
        if (out_fp8) {
          float s = __uint_as_float(smaxu[rloc + r]);
          inv = (s > 0.f) ? 448.f / s : 0.f;
          if (r15 == 0 && wn == 0)
            out_sc[row * 2 + (n0 >> 8)] = (s > 0.f) ? s / 448.f : 1.0f;
        }
#pragma unroll
        for (int nt = 0; nt < 4; ++nt) {
          int c = n0 + wn + nt * 16 + r15;
          float v = acc[mt][nt][r];
          if (out_f32) out_f32[(size_t)row * ldof + c] = v;
          if (out_bf) out_bf[(size_t)row * ldob + c] = f2bf(v);
        }
        if (out_fp8) {
          u32 u01 = (u32)__builtin_amdgcn_cvt_pk_fp8_f32(acc[mt][0][r] * inv,
                                                         acc[mt][1][r] * inv, 0, false);
          u32 u23 = (u32)__builtin_amdgcn_cvt_pk_fp8_f32(acc[mt][2][r] * inv,
                                                         acc[mt][3][r] * inv, 0, false);
          size_t rb = (size_t)row * 512 + n0 + wn + r15;
          out_fp8[rb] = (u8)(u01 & 0xff);
          out_fp8[rb + 16] = (u8)((u01 >> 8) & 0xff);
          out_fp8[rb + 32] = (u8)(u23 & 0xff);
          out_fp8[rb + 48] = (u8)((u23 >> 8) & 0xff);
        }
      }
    }
  }
}

// ------- HYBRID GEMM 128x256 (layers 2/3, K=1024 = 512 fp8 + 512 bf16) ----
// R16: TWO sequential pipelined loops (one dtype each) to kill R15's spill.
// Loop A (8 steps, BK=64 fp8): A2 = h fp8, B = W_root fp8; acc rescale at
// t==4 (scale half0 -> half1). Between loops: acc *= s1*sB[c] (true units).
// Loop B (16 steps, BK=32 bf16): A1 = agg bf16, B = W_rel bf16.

__global__ __launch_bounds__(512, 2) void gemmh(
    const u16* __restrict__ A1, const u8* __restrict__ A2,
    const float* __restrict__ sA2, const u16* __restrict__ Bt1,
    const u8* __restrict__ Bt2, const float* __restrict__ sB,
    const float* __restrict__ bias,
    u16* __restrict__ out_bf, int ldob, float* __restrict__ out_f32, int ldof,
    u8* __restrict__ out_fp8, float* __restrict__ out_sc, int M) {
  __shared__ u8 lA[3][128 * 64];
  __shared__ u8 lB[3][256 * 64];
  __shared__ u32 smaxu[128];
  const int tid = threadIdx.x;
  const int lane = tid & 63;
  const int wv = tid >> 6;
  const int wm = (wv >> 2) * 64;
  const int wn = (wv & 3) * 64;
  const int n0 = blockIdx.x * 256;
  const int m0 = blockIdx.y * 128;
  const int r15 = lane & 15;
  const int quad = lane >> 4;

  if (tid < 128) smaxu[tid] = 0;

  const int arow = tid >> 2;
  const int achk = (tid & 3) ^ ((tid >> 3) & 3);

  auto stage8 = [&](int ts, int b) {
    int kk = ts * 64;
    g2l16(A2 + (size_t)(m0 + arow) * 512 + kk + achk * 16, &lA[b][tid * 16]);
#pragma unroll
    for (int i = 0; i < 2; ++i) {
      int li = tid + i * 512;
      int chk = (li & 3) ^ ((li >> 3) & 3);
      g2l16(Bt2 + (size_t)(n0 + (li >> 2)) * 512 + kk + chk * 16, &lB[b][li * 16]);
    }
  };
  auto stage16 = [&](int ts, int b) {
    int kk = ts * 32;
    g2l16(A1 + (size_t)(m0 + arow) * 512 + kk + achk * 8, &lA[b][tid * 16]);
#pragma unroll
    for (int i = 0; i < 2; ++i) {
      int li = tid + i * 512;
      int chk = (li & 3) ^ ((li >> 3) & 3);
      g2l16(Bt1 + (size_t)(n0 + (li >> 2)) * 512 + kk + chk * 8, &lB[b][li * 16]);
    }
  };

  f32x4 acc[4][4];
#pragma unroll
  for (int i = 0; i < 4; ++i)
#pragma unroll
    for (int j = 0; j < 4; ++j) acc[i][j] = (f32x4){0.f, 0.f, 0.f, 0.f};

  // ---- loop A: fp8, 8 steps ----
  stage8(0, 0);
  stage8(1, 1);
  for (int t = 0; t < 8; ++t) {
    const int cur = t % 3;
    __builtin_amdgcn_s_barrier();
    if (t + 2 < 8) stage8(t + 2, (t + 2) % 3);
    if (t + 2 < 8)      asm volatile("s_waitcnt vmcnt(6)" ::: "memory");
    else if (t + 1 < 8) asm volatile("s_waitcnt vmcnt(3)" ::: "memory");
    else                asm volatile("s_waitcnt vmcnt(0)" ::: "memory");
    __builtin_amdgcn_s_barrier();
    __builtin_amdgcn_sched_barrier(0);
    if (t == 4) {  // h scale half0 -> half1 units
#pragma unroll
      for (int mt = 0; mt < 4; ++mt)
#pragma unroll
        for (int r = 0; r < 4; ++r) {
          int row = m0 + wm + mt * 16 + quad * 4 + r;
          float ra = sA2[row * 2] / sA2[row * 2 + 1];
#pragma unroll
          for (int nt = 0; nt < 4; ++nt) acc[mt][nt][r] *= ra;
        }
    }
#pragma unroll
    for (int ks = 0; ks < 2; ++ks) {
      i64 af[4], bfr[4];
#pragma unroll
      for (int mt = 0; mt < 4; ++mt) {
        int s = (wm + mt * 16 + r15) * 4 + ks * 2 + (quad >> 1);
        af[mt] = *(const i64*)&lA[cur][swz(s) * 16 + (quad & 1) * 8];
      }
#pragma unroll
      for (int nt = 0; nt < 4; ++nt) {
        int s = (wn + nt * 16 + r15) * 4 + ks * 2 + (quad >> 1);
        bfr[nt] = *(const i64*)&lB[cur][swz(s) * 16 + (quad & 1) * 8];
      }
#pragma unroll
      for (int mt = 0; mt < 4; ++mt)
#pragma unroll
        for (int nt = 0; nt < 4; ++nt)
          acc[mt][nt] = __builtin_amdgcn_mfma_f32_16x16x32_fp8_fp8(af[mt], bfr[nt],
                                                                   acc[mt][nt], 0, 0, 0);
    }
  }
  __syncthreads();  // all waves done with loop-A LDS before restaging

  // ---- bf16 prologue overlapped with unit conversion ----
  stage16(0, 0);
  stage16(1, 1);
#pragma unroll
  for (int mt = 0; mt < 4; ++mt)
#pragma unroll
    for (int r = 0; r < 4; ++r) {
      int row = m0 + wm + mt * 16 + quad * 4 + r;
      float s1 = sA2[row * 2 + 1];
#pragma unroll
      for (int nt = 0; nt < 4; ++nt) {
        int c = n0 + wn + nt * 16 + r15;
        acc[mt][nt][r] *= s1 * sB[c];
      }
    }

  // ---- loop B: bf16, 16 steps ----
  for (int t = 0; t < 16; ++t) {
    const int cur = t % 3;
    __builtin_amdgcn_s_barrier();
    if (t + 2 < 16) stage16(t + 2, (t + 2) % 3);
    if (t + 2 < 16)      asm volatile("s_waitcnt vmcnt(6)" ::: "memory");
    else if (t + 1 < 16) asm volatile("s_waitcnt vmcnt(3)" ::: "memory");
    else                 asm volatile("s_waitcnt vmcnt(0)" ::: "memory");
    __builtin_amdgcn_s_barrier();
    __builtin_amdgcn_sched_barrier(0);
    frag8 af[4], bfr[4];
#pragma unroll
    for (int mt = 0; mt < 4; ++mt) {
      int s = (wm + mt * 16 + r15) * 4 + quad;
      af[mt] = *(const frag8*)&lA[cur][swz(s) * 16];
    }
#pragma unroll
    for (int nt = 0; nt < 4; ++nt) {
      int s = (wn + nt * 16 + r15) * 4 + quad;
      bfr[nt] = *(const frag8*)&lB[cur][swz(s) * 16];
    }
#pragma unroll
    for (int mt = 0; mt < 4; ++mt)
#pragma unroll
      for (int nt = 0; nt < 4; ++nt)
        acc[mt][nt] =
            __builtin_amdgcn_mfma_f32_16x16x32_bf16(af[mt], bfr[nt], acc[mt][nt], 0, 0, 0);
  }
  __syncthreads();

#pragma unroll
  for (int mt = 0; mt < 4; ++mt) {
#pragma unroll
    for (int r = 0; r < 4; ++r) {
      float rm = 0.f;
#pragma unroll
      for (int nt = 0; nt < 4; ++nt) {
        int c = n0 + wn + nt * 16 + r15;
        float v = acc[mt][nt][r] + bias[c];
        v = fmaxf(v, 0.f);  // layers 2/3 both relu
        acc[mt][nt][r] = v;
        rm = fmaxf(rm, v);
      }
      if (out_fp8) {
        rm = fmaxf(rm, __shfl_xor(rm, 1));
        rm = fmaxf(rm, __shfl_xor(rm, 2));
        rm = fmaxf(rm, __shfl_xor(rm, 4));
        rm = fmaxf(rm, __shfl_xor(rm, 8));
        if (r15 == 0) atomicMax(&smaxu[wm + mt * 16 + quad * 4 + r], __float_as_uint(rm));
      }
    }
  }
  if (out_fp8) __syncthreads();

#pragma unroll
  for (int mt = 0; mt < 4; ++mt) {
    int rloc = wm + mt * 16 + quad * 4;
#pragma unroll
    for (int r = 0; r < 4; ++r) {
      int row = m0 + rloc + r;
      if (row < M) {
        float inv = 0.f;
        if (out_fp8) {
          float s = __uint_as_float(smaxu[rloc + r]);
          inv = (s > 0.f) ? 448.f / s : 0.f;
          if (r15 == 0 && wn == 0)
            out_sc[row * 2 + (n0 >> 8)] = (s > 0.f) ? s / 448.f : 1.0f;
        }
#pragma unroll
        for (int nt = 0; nt < 4; ++nt) {
          int c = n0 + wn + nt * 16 + r15;
          float v = acc[mt][nt][r];
          if (out_f32) out_f32[(size_t)row * ldof + c] = v;
          if (out_bf) out_bf[(size_t)row * ldob + c] = f2bf(v);
        }
        if (out_fp8) {
          u32 u01 = (u32)__builtin_amdgcn_cvt_pk_fp8_f32(acc[mt][0][r] * inv,
                                                         acc[mt][1][r] * inv, 0, false);
          u32 u23 = (u32)__builtin_amdgcn_cvt_pk_fp8_f32(acc[mt][2][r] * inv,
                                                         acc[mt][3][r] * inv, 0, false);
          size_t rb = (size_t)row * 512 + n0 + wn + r15;
          out_fp8[rb] = (u8)(u01 & 0xff);
          out_fp8[rb + 16] = (u8)((u01 >> 8) & 0xff);
          out_fp8[rb + 32] = (u8)(u23 & 0xff);
          out_fp8[rb + 48] = (u8)((u23 >> 8) & 0xff);
        }
      }
    }
  }
}

// ---------------- head GEMM 128x64 tile, 256 threads ----------------

__global__ __launch_bounds__(256) void gemm64(
    const u16* __restrict__ A1, int lda1, int Ktot, const u16* __restrict__ Bt,
    const float* __restrict__ bias, float* __restrict__ out_f32, int ldof, int M) {
  __shared__ u16 lA[3][128 * 32];
  __shared__ u16 lB[3][64 * 32];
  const int tid = threadIdx.x;
  const int lane = tid & 63;
  const int wv = tid >> 6;
  const int wm = (wv >> 1) * 64;
  const int wn = (wv & 1) * 32;
  const int m0 = blockIdx.x * 128;
  const int r15 = lane & 15;
  const int quad = lane >> 4;

  auto stage = [&](int kk, int b) {
#pragma unroll
    for (int i = 0; i < 2; ++i) {
      int li = tid + i * 256;
      int kc = ((li & 3) ^ ((li >> 3) & 3)) * 8;
      g2l16(A1 + (size_t)(m0 + (li >> 2)) * lda1 + kk + kc, &lA[b][li * 8]);
    }
    {
      int kc = ((tid & 3) ^ ((tid >> 3) & 3)) * 8;
      g2l16(Bt + (size_t)(tid >> 2) * Ktot + (kk + kc), &lB[b][tid * 8]);
    }
  };

  f32x4 acc[4][2];
#pragma unroll
  for (int i = 0; i < 4; ++i)
#pragma unroll
    for (int j = 0; j < 2; ++j) acc[i][j] = (f32x4){0.f, 0.f, 0.f, 0.f};

  const int ntk = Ktot >> 5;
  stage(0, 0);
  stage(32, 1);
  for (int t = 0; t < ntk; ++t) {
    const int cur = t % 3;
    __builtin_amdgcn_s_barrier();
    if (t + 2 < ntk) stage((t + 2) * 32, (t + 2) % 3);
    if (t + 2 < ntk)      asm volatile("s_waitcnt vmcnt(6)" ::: "memory");
    else if (t + 1 < ntk) asm volatile("s_waitcnt vmcnt(3)" ::: "memory");
    else                  asm volatile("s_waitcnt vmcnt(0)" ::: "memory");
    __builtin_amdgcn_s_barrier();
    __builtin_amdgcn_sched_barrier(0);
    frag8 af[4], bfr[2];
#pragma unroll
    for (int mt = 0; mt < 4; ++mt) {
      int s = (wm + mt * 16 + r15) * 4 + quad;
      af[mt] = *(const frag8*)&lA[cur][swz(s) * 8];
    }
#pragma unroll
    for (int nt = 0; nt < 2; ++nt) {
      int s = (wn + nt * 16 + r15) * 4 + quad;
      bfr[nt] = *(const frag8*)&lB[cur][swz(s) * 8];
    }
#pragma unroll
    for (int mt = 0; mt < 4; ++mt)
#pragma unroll
      for (int nt = 0; nt < 2; ++nt)
        acc[mt][nt] =
            __builtin_amdgcn_mfma_f32_16x16x32_bf16(af[mt], bfr[nt], acc[mt][nt], 0, 0, 0);
  }

#pragma unroll
  for (int mt = 0; mt < 4; ++mt) {
    int rbase = m0 + wm + mt * 16 + quad * 4;
#pragma unroll
    for (int r = 0; r < 4; ++r) {
      int row = rbase + r;
      if (row < M) {
#pragma unroll
        for (int nt = 0; nt < 2; ++nt) {
          int c = wn + nt * 16 + r15;
          out_f32[(size_t)row * ldof + c] = acc[mt][nt][r] + bias[c];
        }
      }
    }
  }
}

// ---------------- launch ----------------

extern "C" void kernel_launch(void* const* d_in, const int* in_sizes, int n_in, void* d_out,
                              int out_size, void* d_ws, size_t ws_size, hipStream_t stream) {
  const float* x = (const float*)d_in[0];
  const float* W1r = (const float*)d_in[1];
  const float* b1 = (const float*)d_in[2];
  const float* W1o = (const float*)d_in[3];
  const float* W2r = (const float*)d_in[4];
  const float* b2 = (const float*)d_in[5];
  const float* W2o = (const float*)d_in[6];
  const float* W3r = (const float*)d_in[7];
  const float* b3 = (const float*)d_in[8];
  const float* W3o = (const float*)d_in[9];
  const float* Wl = (const float*)d_in[10];
  const float* bl = (const float*)d_in[11];
  const int* src = (const int*)d_in[12];
  const int* dst = src + NE;

  size_t off = 0;
  char* ws = (char*)d_ws;
  auto take = [&](size_t bytes) -> void* {
    void* p = ws + off;
    off = (off + bytes + 255) & ~(size_t)255;
    return p;
  };
  u16* h13 = (u16*)take((size_t)MPAD * 512 * 2);   // h3 bf16 (head input)
  u16* h2b = (u16*)take((size_t)MPAD * 512 * 2);   // carved: hfp8_b + scb_b
  u16* aggB = (u16*)take((size_t)MPAD * 512 * 2);  // layer1 aggx[.][256] / agg bf16 [.][512]
  u16* aggx = aggB;
  u8* hfp8a = (u8*)take((size_t)MPAD * 512);       // h1 fp8
  float* scba = (float*)take((size_t)MPAD * 2 * 4);
  u8* hfp8b = (u8*)h2b;                                // h2 fp8
  float* scbb = (float*)((char*)h2b + (size_t)MPAD * 512);
  u16* wt1 = (u16*)take((size_t)512 * 256 * 2);
  u16* wt2 = (u16*)take((size_t)512 * 512 * 2);    // W2_rel bf16 [n][512]
  u16* wt3 = (u16*)take((size_t)512 * 512 * 2);    // W3_rel bf16
  u8* wtf2 = (u8*)take((size_t)512 * 512);         // W2_root fp8 [n][512]
  float* sB2 = (float*)take(512 * 4);
  u8* wtf3 = (u8*)take((size_t)512 * 512);         // W3_root fp8
  float* sB3 = (float*)take(512 * 4);
  u16* wtl = (u16*)take((size_t)64 * 512 * 2);
  u32* region = (u32*)take((size_t)NBKT * CAP * 4);
  int* gcur = (int*)take(128 * 4);
  int* bbase = (int*)take(128 * 4);
  int* rs = (int*)take((size_t)(NN + 1) * 4);
  u16* csr = (u16*)take((size_t)NE * 2);

  float* out_logits = (float*)d_out;
  float* out_embed = out_logits + (size_t)NN * 64;

  // binned CSR build
  zero_i32<<<1, 128, 0, stream>>>(gcur, NBKT);
  p1bin<<<(NE + 2047) / 2048, 256, 0, stream>>>(src, dst, gcur, region, NE);
  scan98<<<1, 64, 0, stream>>>(gcur, bbase, rs);
  p2build<<<NBKT, 256, 0, stream>>>(region, gcur, bbase, rs, csr);

  // conversions
  f2bf_x<<<(NN * 32 + 255) / 256, 256, 0, stream>>>((const float4*)x, aggx, NN * 32);
  wtrans<<<(512 * 256 + 255) / 256, 256, 0, stream>>>(W1r, 128, W1o, 128, 512, wt1);
  wtrans<<<(512 * 512 + 255) / 256, 256, 0, stream>>>(W2r, 512, W2r, 0, 512, wt2);
  wtrans<<<(512 * 512 + 255) / 256, 256, 0, stream>>>(W3r, 512, W3r, 0, 512, wt3);
  wtransf8<<<128, 256, 0, stream>>>(W2o, 512, wtf2, sB2);
  wtransf8<<<128, 256, 0, stream>>>(W3o, 512, wtf3, sB3);
  wtrans<<<(64 * 512 + 255) / 256, 256, 0, stream>>>(Wl, 512, Wl, 0, 64, wtl);

  // layer 1 (bf16): agg(x); h1 = relu([agg|x] @ W1 + b1) -> fp8 only
  agg_bf128<<<(NN + 3) / 4, 256, 0, stream>>>(aggx + 128, 256, aggx, 256, rs, csr, NN);
  gemm256<<<dim3(2, GRID_M), 512, 0, stream>>>(aggx, 256, 256, wt1, b1, 1,
                                               (u16*)nullptr, 0, (float*)nullptr, 0,
                                               hfp8a, scba, NN);
  // layer 2: agg(h1 fp8) -> bf16; h2 = relu(agg@W2rel + h1@W2root + b2) -> fp8
  agg_fp8<<<(NN + 3) / 4, 256, 0, stream>>>(hfp8a, scba, aggB, rs, csr, NN);
  gemmh<<<dim3(2, GRID_M), 512, 0, stream>>>(aggB, hfp8a, scba, wt2, wtf2, sB2, b2,
                                             (u16*)nullptr, 0, (float*)nullptr, 0,
                                             hfp8b, scbb, NN);
  // layer 3: agg(h2 fp8); h3 -> bf16 + f32 embed
  agg_fp8<<<(NN + 3) / 4, 256, 0, stream>>>(hfp8b, scbb, aggB, rs, csr, NN);
  gemmh<<<dim3(2, GRID_M), 512, 0, stream>>>(aggB, hfp8b, scbb, wt3, wtf3, sB3, b3,
                                             h13, 512, out_embed, 512,
                                             (u8*)nullptr, (float*)nullptr, NN);
  // head
  gemm64<<<GRID_M, 256, 0, stream>>>(h13, 512, 512, wtl, bl, out_logits, 64, NN);
}

// Round 11
// 742.702 us; speedup vs baseline: 2.3613x; 1.0531x over previous
//
#include <hip/hip_runtime.h>

// GNN1: 3x GraphConv(add) + linear head on MI355X.
// R6 CSR; R7 agg 109us (mem wall); R8-R10 sliced agg LOSS; R11 dbuf
// neutral; R12 chunk-major LOSS; R13 swizzle+depth3 ring neutral (733us,
// known-good); R14 full-fp8 FAILED accuracy; R15 hybrid passed but spilled
// (614us); R16 spill fixed but hybrid still slower than bf16 (125 vs
// 105us - non-scaled fp8 MFMA = bf16 rate; saved bytes weren't the
// bottleneck). REVERTED to R13 bf16 structure.
// R17: (a) GEMMs: depth-2 ring (48.5KB LDS -> 3 blocks/CU, +50% resident
// waves) + swizzle + counted vmcnt(3) - attacks the latency/barrier-bound
// diagnosis (all pipes <20% across 4 structural variants); (b) agg_fp8:
// 8-deep gather unroll (2x memory-level parallelism per wave).

typedef unsigned short u16;
typedef unsigned int u32;
typedef unsigned char u8;

#define NN 50000
#define NE 1600000
#define MPAD 50176
#define GRID_M ((NN + 127) / 128)  // 391
#define NBKT 98
#define CAP 20480
#define STG 18432

using frag8 = __attribute__((ext_vector_type(8))) short;
using f32x4 = __attribute__((ext_vector_type(4))) float;
using f32x2 = __attribute__((ext_vector_type(2))) float;

__device__ __forceinline__ u16 f2bf(float f) {
  u32 u = __float_as_uint(f);
  u32 r = u + 0x7fffu + ((u >> 16) & 1u);
  return (u16)(r >> 16);
}
__device__ __forceinline__ float lo2f(u32 u) { return __uint_as_float(u << 16); }
__device__ __forceinline__ float hi2f(u32 u) { return __uint_as_float(u & 0xffff0000u); }
__device__ __forceinline__ u32 pack2(float a, float b) {
  return (u32)f2bf(a) | ((u32)f2bf(b) << 16);
}

__device__ __forceinline__ void g2l16(const void* g, void* l) {
  __builtin_amdgcn_global_load_lds((const __attribute__((address_space(1))) void*)g,
                                   (__attribute__((address_space(3))) void*)l, 16, 0, 0);
}

// 16B-slot XOR swizzle (involution): chunk bits[1:0] ^= bits[4:3].
__device__ __forceinline__ int swz(int s) { return s ^ ((s >> 3) & 3); }

// ---------------- binned CSR build ----------------

__global__ void zero_i32(int* p, int n) {
  int i = blockIdx.x * 256 + threadIdx.x;
  if (i < n) p[i] = 0;
}

__global__ __launch_bounds__(256) void p1bin(const int* __restrict__ src,
                                             const int* __restrict__ dst,
                                             int* __restrict__ gcur,
                                             u32* __restrict__ region, int ne) {
  __shared__ u32 lbuf[NBKT * 64];
  __shared__ int lcnt[NBKT];
  __shared__ int gbase[NBKT];
  const int tid = threadIdx.x;
  if (tid < NBKT) lcnt[tid] = 0;
  __syncthreads();
  const int base = blockIdx.x * 2048;
#pragma unroll
  for (int j = 0; j < 8; ++j) {
    int i = base + j * 256 + tid;
    if (i < ne) {
      int d = dst[i];
      int s = src[i];
      int b = d >> 9;
      u32 entry = ((u32)(d & 511) << 16) | (u32)s;
      int slot = atomicAdd(&lcnt[b], 1);
      if (slot < 64) lbuf[b * 64 + slot] = entry;
      else {
        int g = atomicAdd(&gcur[b], 1);
        region[(size_t)b * CAP + g] = entry;
      }
    }
  }
  __syncthreads();
  if (tid < NBKT) {
    int c = min(lcnt[tid], 64);
    gbase[tid] = atomicAdd(&gcur[tid], c);
  }
  __syncthreads();
  const int wv = tid >> 6, lane = tid & 63;
  for (int b = wv; b < NBKT; b += 4) {
    int c = min(lcnt[b], 64);
    int gb = gbase[b];
    for (int s2 = lane; s2 < c; s2 += 64)
      region[(size_t)b * CAP + gb + s2] = lbuf[b * 64 + s2];
  }
}

__global__ void scan98(const int* __restrict__ gcur, int* __restrict__ bbase,
                       int* __restrict__ rs) {
  if (threadIdx.x == 0) {
    int run = 0;
    for (int b = 0; b < NBKT; ++b) {
      bbase[b] = run;
      run += gcur[b];
    }
    bbase[NBKT] = run;
    rs[NN] = run;
  }
}

__global__ __launch_bounds__(256) void p2build(const u32* __restrict__ region,
                                               const int* __restrict__ gcnt,
                                               const int* __restrict__ bbase,
                                               int* __restrict__ rs,
                                               u16* __restrict__ csr) {
  __shared__ int cnt[512];
  __shared__ int off[512];
  __shared__ int sh[256];
  __shared__ u16 stg[STG];
  const int b = blockIdx.x, tid = threadIdx.x;
  const int n0 = b * 512;
  const int nnb = min(512, NN - n0);
  const int ec = gcnt[b];
  const int gb = bbase[b];
  const u32* __restrict__ reg = region + (size_t)b * CAP;
  cnt[tid] = 0;
  cnt[tid + 256] = 0;
  __syncthreads();
  for (int i = tid; i < ec; i += 256) atomicAdd(&cnt[reg[i] >> 16], 1);
  __syncthreads();
  int c0 = cnt[2 * tid], c1 = cnt[2 * tid + 1];
  int s = c0 + c1;
  sh[tid] = s;
  __syncthreads();
  for (int o = 1; o < 256; o <<= 1) {
    int t2 = (tid >= o) ? sh[tid - o] : 0;
    __syncthreads();
    sh[tid] += t2;
    __syncthreads();
  }
  int base0 = sh[tid] - s;
  off[2 * tid] = base0;
  off[2 * tid + 1] = base0 + c0;
  __syncthreads();
  if (2 * tid < nnb) rs[n0 + 2 * tid] = gb + off[2 * tid];
  if (2 * tid + 1 < nnb) rs[n0 + 2 * tid + 1] = gb + off[2 * tid + 1];
  cnt[2 * tid] = off[2 * tid];
  cnt[2 * tid + 1] = off[2 * tid + 1];
  __syncthreads();
  for (int i = tid; i < ec; i += 256) {
    u32 e = reg[i];
    int slot = atomicAdd(&cnt[e >> 16], 1);
    u16 sv = (u16)(e & 0xffff);
    if (slot < STG) stg[slot] = sv;
    else csr[gb + slot] = sv;
  }
  __syncthreads();
  for (int i = tid; i < ec && i < STG; i += 256) csr[gb + i] = stg[i];
}

// ---------------- dtype conversion ----------------

__global__ void f2bf_x(const float4* __restrict__ in, u16* __restrict__ out, int n4) {
  int i = blockIdx.x * 256 + threadIdx.x;
  if (i < n4) {
    float4 v = in[i];
    int node = i >> 5;
    int w = i & 31;
    uint2 o;
    o.x = pack2(v.x, v.y);
    o.y = pack2(v.z, v.w);
    *(uint2*)(out + (size_t)node * 256 + 128 + w * 4) = o;
  }
}

__global__ void wtrans(const float* __restrict__ Wa, int Ka, const float* __restrict__ Wb,
                       int Kb, int N, u16* __restrict__ out) {
  int idx = blockIdx.x * 256 + threadIdx.x;
  int Kt = Ka + Kb;
  if (idx >= N * Kt) return;
  int n = idx / Kt;
  int k = idx - n * Kt;
  float v = (k < Ka) ? Wa[(size_t)k * N + n] : Wb[(size_t)(k - Ka) * N + n];
  out[idx] = f2bf(v);
}

// ---------------- layer-1 aggregation: bf16, 128 dims ----------------

__device__ __forceinline__ void accb(f32x2* a, uint4 v, float s) {
  f32x2 sv = (f32x2){s, s};
  f32x2 f;
  f.x = lo2f(v.x); f.y = hi2f(v.x); a[0] += f * sv;
  f.x = lo2f(v.y); f.y = hi2f(v.y); a[1] += f * sv;
  f.x = lo2f(v.z); f.y = hi2f(v.z); a[2] += f * sv;
  f.x = lo2f(v.w); f.y = hi2f(v.w); a[3] += f * sv;
}

__global__ __launch_bounds__(256) void agg_bf128(const u16* __restrict__ H, int ldh,
                                                 u16* __restrict__ Out, int ldo,
                                                 const int* __restrict__ rs,
                                                 const u16* __restrict__ csr, int n) {
  int w = (blockIdx.x * 256 + threadIdx.x) >> 6;
  int lane = threadIdx.x & 63;
  if (w >= n) return;
  int beg = rs[w], end = rs[w + 1];
  const int q = lane >> 4;
  const int lsub = lane & 15;
  f32x2 acc[4];
#pragma unroll
  for (int i = 0; i < 4; ++i) acc[i] = (f32x2){0.f, 0.f};

  int e = beg;
  for (; e + 16 <= end; e += 16) {
    int si[4];
#pragma unroll
    for (int u = 0; u < 4; ++u) si[u] = csr[e + 4 * u + q];
    uint4 v[4];
#pragma unroll
    for (int u = 0; u < 4; ++u)
      v[u] = *(const uint4*)(H + (size_t)si[u] * ldh + lsub * 8);
#pragma unroll
    for (int u = 0; u < 4; ++u) accb(acc, v[u], 1.f);
  }
  if (e < end) {
#pragma unroll
    for (int u = 0; u < 4; ++u) {
      int ei = e + 4 * u + q;
      int ec = min(ei, end - 1);
      int s0 = csr[ec];
      uint4 v = *(const uint4*)(H + (size_t)s0 * ldh + lsub * 8);
      accb(acc, v, (ei < end) ? 1.f : 0.f);
    }
  }
#pragma unroll
  for (int i = 0; i < 4; ++i) {
    acc[i].x += __shfl_xor(acc[i].x, 16);
    acc[i].y += __shfl_xor(acc[i].y, 16);
    acc[i].x += __shfl_xor(acc[i].x, 32);
    acc[i].y += __shfl_xor(acc[i].y, 32);
  }
  if (lane < 32) {
    int qq = lane >> 4;
    uint2 o;
    o.x = pack2(acc[qq * 2].x, acc[qq * 2].y);
    o.y = pack2(acc[qq * 2 + 1].x, acc[qq * 2 + 1].y);
    *(uint2*)(Out + (size_t)w * ldo + (lane & 15) * 8 + qq * 4) = o;
  }
}

// ---------------- 512-dim aggregation: fp8 payload ----------------
// R17: 8-deep unroll - 16 edges / 8x uint4 (512B) in flight per wave.

__device__ __forceinline__ void accp(f32x2* a, uint4 v, float s) {
  f32x2 sv = (f32x2){s, s};
  f32x2 f;
  f = __builtin_amdgcn_cvt_pk_f32_fp8(v.x, false); a[0] += f * sv;
  f = __builtin_amdgcn_cvt_pk_f32_fp8(v.x, true);  a[1] += f * sv;
  f = __builtin_amdgcn_cvt_pk_f32_fp8(v.y, false); a[2] += f * sv;
  f = __builtin_amdgcn_cvt_pk_f32_fp8(v.y, true);  a[3] += f * sv;
  f = __builtin_amdgcn_cvt_pk_f32_fp8(v.z, false); a[4] += f * sv;
  f = __builtin_amdgcn_cvt_pk_f32_fp8(v.z, true);  a[5] += f * sv;
  f = __builtin_amdgcn_cvt_pk_f32_fp8(v.w, false); a[6] += f * sv;
  f = __builtin_amdgcn_cvt_pk_f32_fp8(v.w, true);  a[7] += f * sv;
}

__global__ __launch_bounds__(256) void agg_fp8(const u8* __restrict__ H8,
                                               const float* __restrict__ sc,
                                               u16* __restrict__ Out,
                                               const int* __restrict__ rs,
                                               const u16* __restrict__ csr, int n) {
  int w = (blockIdx.x * 256 + threadIdx.x) >> 6;
  int lane = threadIdx.x & 63;
  if (w >= n) return;
  int beg = rs[w], end = rs[w + 1];
  const int halfe = lane >> 5;
  const int lsub = lane & 31;
  const int shalf = lsub >> 4;
  f32x2 acc[8];
#pragma unroll
  for (int i = 0; i < 8; ++i) acc[i] = (f32x2){0.f, 0.f};

  int e = beg;
  for (; e + 16 <= end; e += 16) {  // 16 edges: 8 uint4 loads in flight
    int si[8];
#pragma unroll
    for (int u = 0; u < 8; ++u) si[u] = csr[e + 2 * u + halfe];
    uint4 v[8];
#pragma unroll
    for (int u = 0; u < 8; ++u)
      v[u] = *(const uint4*)(H8 + (size_t)si[u] * 512 + lsub * 16);
    float cs[8];
#pragma unroll
    for (int u = 0; u < 8; ++u) cs[u] = sc[si[u] * 2 + shalf];
#pragma unroll
    for (int u = 0; u < 8; ++u) accp(acc, v[u], cs[u]);
  }
  for (; e < end; e += 8) {  // clamped 8-edge blocks cover the tail
#pragma unroll
    for (int u = 0; u < 4; ++u) {
      int ei = e + 2 * u + halfe;
      int ec = min(ei, end - 1);
      int s0 = csr[ec];
      uint4 v = *(const uint4*)(H8 + (size_t)s0 * 512 + lsub * 16);
      float c = (ei < end) ? sc[s0 * 2 + shalf] : 0.f;
      accp(acc, v, c);
    }
  }
#pragma unroll
  for (int i = 0; i < 8; ++i) {
    acc[i].x += __shfl_xor(acc[i].x, 32);
    acc[i].y += __shfl_xor(acc[i].y, 32);
  }
  uint4 o;
  if (halfe == 0) {
    o.x = pack2(acc[0].x, acc[0].y);
    o.y = pack2(acc[1].x, acc[1].y);
    o.z = pack2(acc[2].x, acc[2].y);
    o.w = pack2(acc[3].x, acc[3].y);
  } else {
    o.x = pack2(acc[4].x, acc[4].y);
    o.y = pack2(acc[5].x, acc[5].y);
    o.z = pack2(acc[6].x, acc[6].y);
    o.w = pack2(acc[7].x, acc[7].y);
  }
  *(uint4*)(Out + (size_t)w * 512 + lsub * 16 + halfe * 8) = o;
}

// ---------------- GEMM 128x256 tile, 512 threads, 8 waves ----------------
// R17: depth-2 ring (48.5KB LDS -> 3 blocks/CU) + swizzle + vmcnt(3).

__global__ __launch_bounds__(512, 4) void gemm256(
    const u16* __restrict__ A1, int lda1, const u16* __restrict__ A2, int lda2, int K1,
    int Ktot, const u16* __restrict__ Bt, const float* __restrict__ bias, int relu,
    u16* __restrict__ out_bf, int ldob, float* __restrict__ out_f32, int ldof,
    u8* __restrict__ out_fp8, float* __restrict__ out_sc, int M) {
  __shared__ u16 lA[2][128 * 32];
  __shared__ u16 lB[2][256 * 32];
  __shared__ u32 smaxu[128];
  const int tid = threadIdx.x;
  const int lane = tid & 63;
  const int wv = tid >> 6;
  const int wm = (wv >> 2) * 64;
  const int wn = (wv & 3) * 64;
  const int n0 = blockIdx.x * 256;
  const int m0 = blockIdx.y * 128;
  const int r15 = lane & 15;
  const int quad = lane >> 4;

  if (tid < 128) smaxu[tid] = 0;

  const int arow = tid >> 2;
  const int akc = ((tid & 3) ^ ((tid >> 3) & 3)) * 8;

  auto stage = [&](int kk, int b) {
    const u16* Ab;
    int lda;
    if (kk < K1) { Ab = A1 + kk; lda = lda1; }
    else         { Ab = A2 + (kk - K1); lda = lda2; }
    g2l16(Ab + (size_t)(m0 + arow) * lda + akc, &lA[b][tid * 8]);
#pragma unroll
    for (int i = 0; i < 2; ++i) {
      int li = tid + i * 512;
      int kc = ((li & 3) ^ ((li >> 3) & 3)) * 8;
      g2l16(Bt + (size_t)(n0 + (li >> 2)) * Ktot + (kk + kc), &lB[b][li * 8]);
    }
  };

  f32x4 acc[4][4];
#pragma unroll
  for (int i = 0; i < 4; ++i)
#pragma unroll
    for (int j = 0; j < 4; ++j) acc[i][j] = (f32x4){0.f, 0.f, 0.f, 0.f};

  const int ntk = Ktot >> 5;
  stage(0, 0);
  for (int t = 0; t < ntk; ++t) {
    const int cur = t & 1;
    __builtin_amdgcn_s_barrier();  // all waves done reading buf[cur^1]
    if (t + 1 < ntk) stage((t + 1) * 32, cur ^ 1);
    if (t + 1 < ntk) asm volatile("s_waitcnt vmcnt(3)" ::: "memory");
    else             asm volatile("s_waitcnt vmcnt(0)" ::: "memory");
    __builtin_amdgcn_s_barrier();  // buf[cur] fully written by all waves
    __builtin_amdgcn_sched_barrier(0);
    frag8 af[4], bfr[4];
#pragma unroll
    for (int mt = 0; mt < 4; ++mt) {
      int s = (wm + mt * 16 + r15) * 4 + quad;
      af[mt] = *(const frag8*)&lA[cur][swz(s) * 8];
    }
#pragma unroll
    for (int nt = 0; nt < 4; ++nt) {
      int s = (wn + nt * 16 + r15) * 4 + quad;
      bfr[nt] = *(const frag8*)&lB[cur][swz(s) * 8];
    }
#pragma unroll
    for (int mt = 0; mt < 4; ++mt)
#pragma unroll
      for (int nt = 0; nt < 4; ++nt)
        acc[mt][nt] =
            __builtin_amdgcn_mfma_f32_16x16x32_bf16(af[mt], bfr[nt], acc[mt][nt], 0, 0, 0);
  }
  __syncthreads();

#pragma unroll
  for (int mt = 0; mt < 4; ++mt) {
#pragma unroll
    for (int r = 0; r < 4; ++r) {
      float rm = 0.f;
#pragma unroll
      for (int nt = 0; nt < 4; ++nt) {
        int c = n0 + wn + nt * 16 + r15;
        float v = acc[mt][nt][r] + bias[c];
        if (relu) v = fmaxf(v, 0.f);
        acc[mt][nt][r] = v;
        rm = fmaxf(rm, v);
      }
      if (out_fp8) {
        rm = fmaxf(rm, __shfl_xor(rm, 1));
        rm = fmaxf(rm, __shfl_xor(rm, 2));
        rm = fmaxf(rm, __shfl_xor(rm, 4));
        rm = fmaxf(rm, __shfl_xor(rm, 8));
        if (r15 == 0) atomicMax(&smaxu[wm + mt * 16 + quad * 4 + r], __float_as_uint(rm));
      }
    }
  }
  if (out_fp8) __syncthreads();

#pragma unroll
  for (int mt = 0; mt < 4; ++mt) {
    int rloc = wm + mt * 16 + quad * 4;
#pragma unroll
    for (int r = 0; r < 4; ++r) {
      int row = m0 + rloc + r;
      if (row < M) {
        float inv = 0.f;
        if (out_fp8) {
          float s = __uint_as_float(smaxu[rloc + r]);
          inv = (s > 0.f) ? 448.f / s : 0.f;
          if (r15 == 0 && wn == 0)
            out_sc[row * 2 + (n0 >> 8)] = (s > 0.f) ? s / 448.f : 0.f;
        }
#pragma unroll
        for (int nt = 0; nt < 4; ++nt) {
          int c = n0 + wn + nt * 16 + r15;
          float v = acc[mt][nt][r];
          if (out_f32) out_f32[(size_t)row * ldof + c] = v;
          if (out_bf) out_bf[(size_t)row * ldob + c] = f2bf(v);
        }
        if (out_fp8) {
          u32 u01 = (u32)__builtin_amdgcn_cvt_pk_fp8_f32(acc[mt][0][r] * inv,
                                                         acc[mt][1][r] * inv, 0, false);
          u32 u23 = (u32)__builtin_amdgcn_cvt_pk_fp8_f32(acc[mt][2][r] * inv,
                                                         acc[mt][3][r] * inv, 0, false);
          size_t rb = (size_t)row * 512 + n0 + wn + r15;
          out_fp8[rb] = (u8)(u01 & 0xff);
          out_fp8[rb + 16] = (u8)((u01 >> 8) & 0xff);
          out_fp8[rb + 32] = (u8)(u23 & 0xff);
          out_fp8[rb + 48] = (u8)((u23 >> 8) & 0xff);
        }
      }
    }
  }
}

// ---------------- head GEMM 128x64 tile, 256 threads ----------------
// R17: depth-2 ring (20KB LDS -> 8 blocks/CU) + swizzle + vmcnt(3).

__global__ __launch_bounds__(256) void gemm64(
    const u16* __restrict__ A1, int lda1, int Ktot, const u16* __restrict__ Bt,
    const float* __restrict__ bias, float* __restrict__ out_f32, int ldof, int M) {
  __shared__ u16 lA[2][128 * 32];
  __shared__ u16 lB[2][64 * 32];
  const int tid = threadIdx.x;
  const int lane = tid & 63;
  const int wv = tid >> 6;
  const int wm = (wv >> 1) * 64;
  const int wn = (wv & 1) * 32;
  const int m0 = blockIdx.x * 128;
  const int r15 = lane & 15;
  const int quad = lane >> 4;

  auto stage = [&](int kk, int b) {
#pragma unroll
    for (int i = 0; i < 2; ++i) {
      int li = tid + i * 256;
      int kc = ((li & 3) ^ ((li >> 3) & 3)) * 8;
      g2l16(A1 + (size_t)(m0 + (li >> 2)) * lda1 + kk + kc, &lA[b][li * 8]);
    }
    {
      int kc = ((tid & 3) ^ ((tid >> 3) & 3)) * 8;
      g2l16(Bt + (size_t)(tid >> 2) * Ktot + (kk + kc), &lB[b][tid * 8]);
    }
  };

  f32x4 acc[4][2];
#pragma unroll
  for (int i = 0; i < 4; ++i)
#pragma unroll
    for (int j = 0; j < 2; ++j) acc[i][j] = (f32x4){0.f, 0.f, 0.f, 0.f};

  const int ntk = Ktot >> 5;
  stage(0, 0);
  for (int t = 0; t < ntk; ++t) {
    const int cur = t & 1;
    __builtin_amdgcn_s_barrier();
    if (t + 1 < ntk) stage((t + 1) * 32, cur ^ 1);
    if (t + 1 < ntk) asm volatile("s_waitcnt vmcnt(3)" ::: "memory");
    else             asm volatile("s_waitcnt vmcnt(0)" ::: "memory");
    __builtin_amdgcn_s_barrier();
    __builtin_amdgcn_sched_barrier(0);
    frag8 af[4], bfr[2];
#pragma unroll
    for (int mt = 0; mt < 4; ++mt) {
      int s = (wm + mt * 16 + r15) * 4 + quad;
      af[mt] = *(const frag8*)&lA[cur][swz(s) * 8];
    }
#pragma unroll
    for (int nt = 0; nt < 2; ++nt) {
      int s = (wn + nt * 16 + r15) * 4 + quad;
      bfr[nt] = *(const frag8*)&lB[cur][swz(s) * 8];
    }
#pragma unroll
    for (int mt = 0; mt < 4; ++mt)
#pragma unroll
      for (int nt = 0; nt < 2; ++nt)
        acc[mt][nt] =
            __builtin_amdgcn_mfma_f32_16x16x32_bf16(af[mt], bfr[nt], acc[mt][nt], 0, 0, 0);
  }

#pragma unroll
  for (int mt = 0; mt < 4; ++mt) {
    int rbase = m0 + wm + mt * 16 + quad * 4;
#pragma unroll
    for (int r = 0; r < 4; ++r) {
      int row = rbase + r;
      if (row < M) {
#pragma unroll
        for (int nt = 0; nt < 2; ++nt) {
          int c = wn + nt * 16 + r15;
          out_f32[(size_t)row * ldof + c] = acc[mt][nt][r] + bias[c];
        }
      }
    }
  }
}

// ---------------- launch ----------------

extern "C" void kernel_launch(void* const* d_in, const int* in_sizes, int n_in, void* d_out,
                              int out_size, void* d_ws, size_t ws_size, hipStream_t stream) {
  const float* x = (const float*)d_in[0];
  const float* W1r = (const float*)d_in[1];
  const float* b1 = (const float*)d_in[2];
  const float* W1o = (const float*)d_in[3];
  const float* W2r = (const float*)d_in[4];
  const float* b2 = (const float*)d_in[5];
  const float* W2o = (const float*)d_in[6];
  const float* W3r = (const float*)d_in[7];
  const float* b3 = (const float*)d_in[8];
  const float* W3o = (const float*)d_in[9];
  const float* Wl = (const float*)d_in[10];
  const float* bl = (const float*)d_in[11];
  const int* src = (const int*)d_in[12];
  const int* dst = src + NE;

  size_t off = 0;
  char* ws = (char*)d_ws;
  auto take = [&](size_t bytes) -> void* {
    void* p = ws + off;
    off = (off + bytes + 255) & ~(size_t)255;
    return p;
  };
  u16* h13 = (u16*)take((size_t)MPAD * 512 * 2);   // h1, later h3 (bf16)
  u16* h2 = (u16*)take((size_t)MPAD * 512 * 2);    // h2 (bf16)
  u16* aggB = (u16*)take((size_t)MPAD * 512 * 2);  // layer1: aggx[node][256]; later agg512
  u16* aggx = aggB;
  u8* hfp8 = (u8*)take((size_t)MPAD * 512);        // h1 fp8, reused for h2 fp8
  float* scb = (float*)take((size_t)MPAD * 2 * 4); // per (row, half) scales
  u16* wt1 = (u16*)take((size_t)512 * 256 * 2);
  u16* wt2 = (u16*)take((size_t)512 * 1024 * 2);
  u16* wt3 = (u16*)take((size_t)512 * 1024 * 2);
  u16* wtl = (u16*)take((size_t)64 * 512 * 2);
  u32* region = (u32*)take((size_t)NBKT * CAP * 4);
  int* gcur = (int*)take(128 * 4);
  int* bbase = (int*)take(128 * 4);
  int* rs = (int*)take((size_t)(NN + 1) * 4);
  u16* csr = (u16*)take((size_t)NE * 2);

  float* out_logits = (float*)d_out;
  float* out_embed = out_logits + (size_t)NN * 64;

  // binned CSR build
  zero_i32<<<1, 128, 0, stream>>>(gcur, NBKT);
  p1bin<<<(NE + 2047) / 2048, 256, 0, stream>>>(src, dst, gcur, region, NE);
  scan98<<<1, 64, 0, stream>>>(gcur, bbase, rs);
  p2build<<<NBKT, 256, 0, stream>>>(region, gcur, bbase, rs, csr);

  // conversions
  f2bf_x<<<(NN * 32 + 255) / 256, 256, 0, stream>>>((const float4*)x, aggx, NN * 32);
  wtrans<<<(512 * 256 + 255) / 256, 256, 0, stream>>>(W1r, 128, W1o, 128, 512, wt1);
  wtrans<<<(512 * 1024 + 255) / 256, 256, 0, stream>>>(W2r, 512, W2o, 512, 512, wt2);
  wtrans<<<(512 * 1024 + 255) / 256, 256, 0, stream>>>(W3r, 512, W3o, 512, 512, wt3);
  wtrans<<<(64 * 512 + 255) / 256, 256, 0, stream>>>(Wl, 512, Wl, 0, 64, wtl);

  // layer 1: agg(x) -> aggx[:,0:128]; h1 = relu([agg|x] @ W1 + b1) -> bf16 + fp8
  agg_bf128<<<(NN + 3) / 4, 256, 0, stream>>>(aggx + 128, 256, aggx, 256, rs, csr, NN);
  gemm256<<<dim3(2, GRID_M), 512, 0, stream>>>(aggx, 256, aggx, 256, 256, 256, wt1, b1, 1,
                                               h13, 512, (float*)nullptr, 0, hfp8, scb, NN);
  // layer 2: fp8 gather of h1; h2 -> bf16 + fp8
  agg_fp8<<<(NN + 3) / 4, 256, 0, stream>>>(hfp8, scb, aggB, rs, csr, NN);
  gemm256<<<dim3(2, GRID_M), 512, 0, stream>>>(aggB, 512, h13, 512, 512, 1024, wt2, b2, 1,
                                               h2, 512, (float*)nullptr, 0, hfp8, scb, NN);
  // layer 3: fp8 gather of h2; h3 -> bf16 + f32 embed
  agg_fp8<<<(NN + 3) / 4, 256, 0, stream>>>(hfp8, scb, aggB, rs, csr, NN);
  gemm256<<<dim3(2, GRID_M), 512, 0, stream>>>(aggB, 512, h2, 512, 512, 1024, wt3, b3, 1,
                                               h13, 512, out_embed, 512, (u8*)nullptr,
                                               (float*)nullptr, NN);
  // head
  gemm64<<<GRID_M, 256, 0, stream>>>(h13, 512, 512, wtl, bl, out_logits, 64, NN);
}

// Round 12
// 722.482 us; speedup vs baseline: 2.4274x; 1.0280x over previous
//
#include <hip/hip_runtime.h>

// GNN1: 3x GraphConv(add) + linear head on MI355X.
// FINAL (R18 = revert to R11, best measured 733.0us):
// Session findings: agg_fp8 pinned at ~3.8TB/s effective across 3 variants
// (512B-random-gather mem-system wall; logical 7.4TB/s via L2/L3);
// gemm256 pinned at 105-125us across 6 structural variants (2-barrier
// K-loop schedule limit; no pipe >20%); fp8 GEMM = bf16 rate (non-scaled)
// so byte-halving didn't pay; dim-sliced agg and chunk-major staging both
// regressed. Best structure: R7 wide-load agg + 2-phase dbuf GEMMs.

typedef unsigned short u16;
typedef unsigned int u32;
typedef unsigned char u8;

#define NN 50000
#define NE 1600000
#define MPAD 50176
#define GRID_M ((NN + 127) / 128)  // 391
#define NBKT 98                    // 512-node buckets
#define CAP 20480                  // region capacity per bucket (mean 16327, sigma 127)
#define STG 18432                  // pass-2 LDS csr staging entries

using frag8 = __attribute__((ext_vector_type(8))) short;
using f32x4 = __attribute__((ext_vector_type(4))) float;
using f32x2 = __attribute__((ext_vector_type(2))) float;

__device__ __forceinline__ u16 f2bf(float f) {
  u32 u = __float_as_uint(f);
  u32 r = u + 0x7fffu + ((u >> 16) & 1u);
  return (u16)(r >> 16);
}
__device__ __forceinline__ float lo2f(u32 u) { return __uint_as_float(u << 16); }
__device__ __forceinline__ float hi2f(u32 u) { return __uint_as_float(u & 0xffff0000u); }
__device__ __forceinline__ u32 pack2(float a, float b) {
  return (u32)f2bf(a) | ((u32)f2bf(b) << 16);
}

__device__ __forceinline__ void g2l16(const void* g, void* l) {
  __builtin_amdgcn_global_load_lds((const __attribute__((address_space(1))) void*)g,
                                   (__attribute__((address_space(3))) void*)l, 16, 0, 0);
}

// ---------------- binned CSR build ----------------

__global__ void zero_i32(int* p, int n) {
  int i = blockIdx.x * 256 + threadIdx.x;
  if (i < n) p[i] = 0;
}

// pass 1: bin edges into per-bucket regions; LDS staging for coalesced flush
__global__ __launch_bounds__(256) void p1bin(const int* __restrict__ src,
                                             const int* __restrict__ dst,
                                             int* __restrict__ gcur,
                                             u32* __restrict__ region, int ne) {
  __shared__ u32 lbuf[NBKT * 64];
  __shared__ int lcnt[NBKT];
  __shared__ int gbase[NBKT];
  const int tid = threadIdx.x;
  if (tid < NBKT) lcnt[tid] = 0;
  __syncthreads();
  const int base = blockIdx.x * 2048;
#pragma unroll
  for (int j = 0; j < 8; ++j) {
    int i = base + j * 256 + tid;
    if (i < ne) {
      int d = dst[i];
      int s = src[i];
      int b = d >> 9;
      u32 entry = ((u32)(d & 511) << 16) | (u32)s;
      int slot = atomicAdd(&lcnt[b], 1);
      if (slot < 64) lbuf[b * 64 + slot] = entry;
      else {  // overflow (ultra-rare): direct global append
        int g = atomicAdd(&gcur[b], 1);
        region[(size_t)b * CAP + g] = entry;
      }
    }
  }
  __syncthreads();
  if (tid < NBKT) {
    int c = min(lcnt[tid], 64);
    gbase[tid] = atomicAdd(&gcur[tid], c);
  }
  __syncthreads();
  const int wv = tid >> 6, lane = tid & 63;
  for (int b = wv; b < NBKT; b += 4) {
    int c = min(lcnt[b], 64);
    int gb = gbase[b];
    for (int s2 = lane; s2 < c; s2 += 64)
      region[(size_t)b * CAP + gb + s2] = lbuf[b * 64 + s2];
  }
}

__global__ void scan98(const int* __restrict__ gcur, int* __restrict__ bbase,
                       int* __restrict__ rs) {
  if (threadIdx.x == 0) {
    int run = 0;
    for (int b = 0; b < NBKT; ++b) {
      bbase[b] = run;
      run += gcur[b];
    }
    bbase[NBKT] = run;
    rs[NN] = run;  // == NE
  }
}

// pass 2: one block per bucket -> rs + csr (coalesced via LDS staging)
__global__ __launch_bounds__(256) void p2build(const u32* __restrict__ region,
                                               const int* __restrict__ gcnt,
                                               const int* __restrict__ bbase,
                                               int* __restrict__ rs,
                                               u16* __restrict__ csr) {
  __shared__ int cnt[512];
  __shared__ int off[512];
  __shared__ int sh[256];
  __shared__ u16 stg[STG];
  const int b = blockIdx.x, tid = threadIdx.x;
  const int n0 = b * 512;
  const int nnb = min(512, NN - n0);
  const int ec = gcnt[b];
  const int gb = bbase[b];
  const u32* __restrict__ reg = region + (size_t)b * CAP;
  cnt[tid] = 0;
  cnt[tid + 256] = 0;
  __syncthreads();
  for (int i = tid; i < ec; i += 256) atomicAdd(&cnt[reg[i] >> 16], 1);
  __syncthreads();
  int c0 = cnt[2 * tid], c1 = cnt[2 * tid + 1];
  int s = c0 + c1;
  sh[tid] = s;
  __syncthreads();
  for (int o = 1; o < 256; o <<= 1) {
    int t2 = (tid >= o) ? sh[tid - o] : 0;
    __syncthreads();
    sh[tid] += t2;
    __syncthreads();
  }
  int base0 = sh[tid] - s;
  off[2 * tid] = base0;
  off[2 * tid + 1] = base0 + c0;
  __syncthreads();
  if (2 * tid < nnb) rs[n0 + 2 * tid] = gb + off[2 * tid];
  if (2 * tid + 1 < nnb) rs[n0 + 2 * tid + 1] = gb + off[2 * tid + 1];
  cnt[2 * tid] = off[2 * tid];  // reuse cnt[] as running cursors
  cnt[2 * tid + 1] = off[2 * tid + 1];
  __syncthreads();
  for (int i = tid; i < ec; i += 256) {
    u32 e = reg[i];
    int slot = atomicAdd(&cnt[e >> 16], 1);
    u16 sv = (u16)(e & 0xffff);
    if (slot < STG) stg[slot] = sv;
    else csr[gb + slot] = sv;  // staging overflow fallback
  }
  __syncthreads();
  for (int i = tid; i < ec && i < STG; i += 256) csr[gb + i] = stg[i];
}

// ---------------- dtype conversion ----------------

// x f32 [NN][128] -> bf16 into aggx[node][256] upper half (offset 128)
__global__ void f2bf_x(const float4* __restrict__ in, u16* __restrict__ out, int n4) {
  int i = blockIdx.x * 256 + threadIdx.x;
  if (i < n4) {
    float4 v = in[i];
    int node = i >> 5;
    int w = i & 31;
    uint2 o;
    o.x = pack2(v.x, v.y);
    o.y = pack2(v.z, v.w);
    *(uint2*)(out + (size_t)node * 256 + 128 + w * 4) = o;
  }
}

__global__ void wtrans(const float* __restrict__ Wa, int Ka, const float* __restrict__ Wb,
                       int Kb, int N, u16* __restrict__ out) {
  int idx = blockIdx.x * 256 + threadIdx.x;
  int Kt = Ka + Kb;
  if (idx >= N * Kt) return;
  int n = idx / Kt;
  int k = idx - n * Kt;
  float v = (k < Ka) ? Wa[(size_t)k * N + n] : Wb[(size_t)(k - Ka) * N + n];
  out[idx] = f2bf(v);
}

// ---------------- layer-1 aggregation: bf16, 128 dims ----------------
// 4 edges per wave-load (16 lanes x 16B cover one 256B row), f32x2 packed
// accumulate, 4-deep unroll (16 edges in flight), clamped final block.

__device__ __forceinline__ void accb(f32x2* a, uint4 v, float s) {
  f32x2 sv = (f32x2){s, s};
  f32x2 f;
  f.x = lo2f(v.x); f.y = hi2f(v.x); a[0] += f * sv;
  f.x = lo2f(v.y); f.y = hi2f(v.y); a[1] += f * sv;
  f.x = lo2f(v.z); f.y = hi2f(v.z); a[2] += f * sv;
  f.x = lo2f(v.w); f.y = hi2f(v.w); a[3] += f * sv;
}

__global__ __launch_bounds__(256) void agg_bf128(const u16* __restrict__ H, int ldh,
                                                 u16* __restrict__ Out, int ldo,
                                                 const int* __restrict__ rs,
                                                 const u16* __restrict__ csr, int n) {
  int w = (blockIdx.x * 256 + threadIdx.x) >> 6;
  int lane = threadIdx.x & 63;
  if (w >= n) return;
  int beg = rs[w], end = rs[w + 1];
  const int q = lane >> 4;     // edge slot within quad (0..3)
  const int lsub = lane & 15;  // 16B chunk within row (8 bf16 dims)
  f32x2 acc[4];
#pragma unroll
  for (int i = 0; i < 4; ++i) acc[i] = (f32x2){0.f, 0.f};

  int e = beg;
  for (; e + 16 <= end; e += 16) {  // full blocks: 16 edges, all valid
    int si[4];
#pragma unroll
    for (int u = 0; u < 4; ++u) si[u] = csr[e + 4 * u + q];
    uint4 v[4];
#pragma unroll
    for (int u = 0; u < 4; ++u)
      v[u] = *(const uint4*)(H + (size_t)si[u] * ldh + lsub * 8);
#pragma unroll
    for (int u = 0; u < 4; ++u) accb(acc, v[u], 1.f);
  }
  if (e < end) {  // one clamped block covers the tail (invalid lanes weight 0)
#pragma unroll
    for (int u = 0; u < 4; ++u) {
      int ei = e + 4 * u + q;
      int ec = min(ei, end - 1);
      int s0 = csr[ec];
      uint4 v = *(const uint4*)(H + (size_t)s0 * ldh + lsub * 8);
      accb(acc, v, (ei < end) ? 1.f : 0.f);
    }
  }
  // reduce across the 4 edge slots (lanes sharing lane&15 hold same dims)
#pragma unroll
  for (int i = 0; i < 4; ++i) {
    acc[i].x += __shfl_xor(acc[i].x, 16);
    acc[i].y += __shfl_xor(acc[i].y, 16);
    acc[i].x += __shfl_xor(acc[i].x, 32);
    acc[i].y += __shfl_xor(acc[i].y, 32);
  }
  if (lane < 32) {
    int qq = lane >> 4;  // 0: dims +0..3, 1: dims +4..7
    uint2 o;
    o.x = pack2(acc[qq * 2].x, acc[qq * 2].y);
    o.y = pack2(acc[qq * 2 + 1].x, acc[qq * 2 + 1].y);
    *(uint2*)(Out + (size_t)w * ldo + (lane & 15) * 8 + qq * 4) = o;
  }
}

// ---------------- 512-dim aggregation: fp8 payload ----------------
// 2 edges per wave-load (32 lanes x 16B cover one 512B row), f32x2 packed
// accumulate, 4-deep unroll (8 edges / 4KB in flight), clamped final block.

__device__ __forceinline__ void accp(f32x2* a, uint4 v, float s) {
  f32x2 sv = (f32x2){s, s};
  f32x2 f;
  f = __builtin_amdgcn_cvt_pk_f32_fp8(v.x, false); a[0] += f * sv;
  f = __builtin_amdgcn_cvt_pk_f32_fp8(v.x, true);  a[1] += f * sv;
  f = __builtin_amdgcn_cvt_pk_f32_fp8(v.y, false); a[2] += f * sv;
  f = __builtin_amdgcn_cvt_pk_f32_fp8(v.y, true);  a[3] += f * sv;
  f = __builtin_amdgcn_cvt_pk_f32_fp8(v.z, false); a[4] += f * sv;
  f = __builtin_amdgcn_cvt_pk_f32_fp8(v.z, true);  a[5] += f * sv;
  f = __builtin_amdgcn_cvt_pk_f32_fp8(v.w, false); a[6] += f * sv;
  f = __builtin_amdgcn_cvt_pk_f32_fp8(v.w, true);  a[7] += f * sv;
}

__global__ __launch_bounds__(256) void agg_fp8(const u8* __restrict__ H8,
                                               const float* __restrict__ sc,
                                               u16* __restrict__ Out,
                                               const int* __restrict__ rs,
                                               const u16* __restrict__ csr, int n) {
  int w = (blockIdx.x * 256 + threadIdx.x) >> 6;
  int lane = threadIdx.x & 63;
  if (w >= n) return;
  int beg = rs[w], end = rs[w + 1];
  const int halfe = lane >> 5;  // which edge of the pair
  const int lsub = lane & 31;   // 16B chunk within row (16 fp8 dims)
  const int shalf = lsub >> 4;  // scale half (dims<256 vs >=256)
  f32x2 acc[8];
#pragma unroll
  for (int i = 0; i < 8; ++i) acc[i] = (f32x2){0.f, 0.f};

  int e = beg;
  for (; e + 8 <= end; e += 8) {  // full blocks: 8 edges, all valid
    int si[4];
#pragma unroll
    for (int u = 0; u < 4; ++u) si[u] = csr[e + 2 * u + halfe];
    uint4 v[4];
#pragma unroll
    for (int u = 0; u < 4; ++u)
      v[u] = *(const uint4*)(H8 + (size_t)si[u] * 512 + lsub * 16);
    float cs[4];
#pragma unroll
    for (int u = 0; u < 4; ++u) cs[u] = sc[si[u] * 2 + shalf];
#pragma unroll
    for (int u = 0; u < 4; ++u) accp(acc, v[u], cs[u]);
  }
  if (e < end) {  // one clamped block covers the tail (invalid lanes scale 0)
#pragma unroll
    for (int u = 0; u < 4; ++u) {
      int ei = e + 2 * u + halfe;
      int ec = min(ei, end - 1);
      int s0 = csr[ec];
      uint4 v = *(const uint4*)(H8 + (size_t)s0 * 512 + lsub * 16);
      float c = (ei < end) ? sc[s0 * 2 + shalf] : 0.f;
      accp(acc, v, c);
    }
  }
  // combine the two edge halves (lanes l and l^32 hold the same dims)
#pragma unroll
  for (int i = 0; i < 8; ++i) {
    acc[i].x += __shfl_xor(acc[i].x, 32);
    acc[i].y += __shfl_xor(acc[i].y, 32);
  }
  uint4 o;
  if (halfe == 0) {
    o.x = pack2(acc[0].x, acc[0].y);
    o.y = pack2(acc[1].x, acc[1].y);
    o.z = pack2(acc[2].x, acc[2].y);
    o.w = pack2(acc[3].x, acc[3].y);
  } else {
    o.x = pack2(acc[4].x, acc[4].y);
    o.y = pack2(acc[5].x, acc[5].y);
    o.z = pack2(acc[6].x, acc[6].y);
    o.w = pack2(acc[7].x, acc[7].y);
  }
  *(uint4*)(Out + (size_t)w * 512 + lsub * 16 + halfe * 8) = o;
}

// ---------------- GEMM 128x256 tile, 512 threads, 8 waves ----------------
// 2-phase double-buffered K-loop: stage tile t+1 while computing tile t.

__global__ __launch_bounds__(512, 4) void gemm256(
    const u16* __restrict__ A1, int lda1, const u16* __restrict__ A2, int lda2, int K1,
    int Ktot, const u16* __restrict__ Bt, const float* __restrict__ bias, int relu,
    u16* __restrict__ out_bf, int ldob, float* __restrict__ out_f32, int ldof,
    u8* __restrict__ out_fp8, float* __restrict__ out_sc, int M) {
  __shared__ u16 lA[2][128 * 32];
  __shared__ u16 lB[2][256 * 32];
  __shared__ u32 smaxu[128];
  const int tid = threadIdx.x;
  const int lane = tid & 63;
  const int wv = tid >> 6;           // 0..7
  const int wm = (wv >> 2) * 64;     // 0,64
  const int wn = (wv & 3) * 64;      // 0,64,128,192
  const int n0 = blockIdx.x * 256;
  const int m0 = blockIdx.y * 128;
  const int r15 = lane & 15;
  const int quad = lane >> 4;

  if (tid < 128) smaxu[tid] = 0;  // covered by prologue __syncthreads

  const int arow = tid >> 2;
  const int akc = (tid & 3) * 8;

  auto stage = [&](int kk, int b) {
    const u16* Ab;
    int lda;
    if (kk < K1) { Ab = A1 + kk; lda = lda1; }
    else         { Ab = A2 + (kk - K1); lda = lda2; }
    g2l16(Ab + (size_t)(m0 + arow) * lda + akc, &lA[b][tid * 8]);
#pragma unroll
    for (int i = 0; i < 2; ++i) {
      int li = tid + i * 512;
      g2l16(Bt + (size_t)(n0 + (li >> 2)) * Ktot + (kk + (li & 3) * 8), &lB[b][li * 8]);
    }
  };

  f32x4 acc[4][4];
#pragma unroll
  for (int i = 0; i < 4; ++i)
#pragma unroll
    for (int j = 0; j < 4; ++j) acc[i][j] = (f32x4){0.f, 0.f, 0.f, 0.f};

  stage(0, 0);
  __syncthreads();  // drains vmcnt -> buf0 ready
  const int ntk = Ktot >> 5;
  for (int t = 0; t < ntk; ++t) {
    const int cur = t & 1;
    if (t + 1 < ntk) stage((t + 1) * 32, cur ^ 1);  // issue next-tile loads
    frag8 af[4], bfr[4];
#pragma unroll
    for (int mt = 0; mt < 4; ++mt)
      af[mt] = *(const frag8*)&lA[cur][(wm + mt * 16 + r15) * 32 + quad * 8];
#pragma unroll
    for (int nt = 0; nt < 4; ++nt)
      bfr[nt] = *(const frag8*)&lB[cur][(wn + nt * 16 + r15) * 32 + quad * 8];
#pragma unroll
    for (int mt = 0; mt < 4; ++mt)
#pragma unroll
      for (int nt = 0; nt < 4; ++nt)
        acc[mt][nt] =
            __builtin_amdgcn_mfma_f32_16x16x32_bf16(af[mt], bfr[nt], acc[mt][nt], 0, 0, 0);
    __syncthreads();  // drains next-tile loads + guards buffer reuse
  }

#pragma unroll
  for (int mt = 0; mt < 4; ++mt) {
#pragma unroll
    for (int r = 0; r < 4; ++r) {
      float rm = 0.f;
#pragma unroll
      for (int nt = 0; nt < 4; ++nt) {
        int c = n0 + wn + nt * 16 + r15;
        float v = acc[mt][nt][r] + bias[c];
        if (relu) v = fmaxf(v, 0.f);
        acc[mt][nt][r] = v;
        rm = fmaxf(rm, v);
      }
      if (out_fp8) {
        rm = fmaxf(rm, __shfl_xor(rm, 1));
        rm = fmaxf(rm, __shfl_xor(rm, 2));
        rm = fmaxf(rm, __shfl_xor(rm, 4));
        rm = fmaxf(rm, __shfl_xor(rm, 8));
        if (r15 == 0) atomicMax(&smaxu[wm + mt * 16 + quad * 4 + r], __float_as_uint(rm));
      }
    }
  }
  if (out_fp8) __syncthreads();

#pragma unroll
  for (int mt = 0; mt < 4; ++mt) {
    int rloc = wm + mt * 16 + quad * 4;
#pragma unroll
    for (int r = 0; r < 4; ++r) {
      int row = m0 + rloc + r;
      if (row < M) {
        float inv = 0.f;
        if (out_fp8) {
          float s = __uint_as_float(smaxu[rloc + r]);
          inv = (s > 0.f) ? 448.f / s : 0.f;
          if (r15 == 0 && wn == 0)
            out_sc[row * 2 + (n0 >> 8)] = (s > 0.f) ? s / 448.f : 0.f;
        }
#pragma unroll
        for (int nt = 0; nt < 4; ++nt) {
          int c = n0 + wn + nt * 16 + r15;
          float v = acc[mt][nt][r];
          if (out_f32) out_f32[(size_t)row * ldof + c] = v;
          if (out_bf) out_bf[(size_t)row * ldob + c] = f2bf(v);
        }
        if (out_fp8) {
          u32 u01 = (u32)__builtin_amdgcn_cvt_pk_fp8_f32(acc[mt][0][r] * inv,
                                                         acc[mt][1][r] * inv, 0, false);
          u32 u23 = (u32)__builtin_amdgcn_cvt_pk_fp8_f32(acc[mt][2][r] * inv,
                                                         acc[mt][3][r] * inv, 0, false);
          size_t rb = (size_t)row * 512 + n0 + wn + r15;
          out_fp8[rb] = (u8)(u01 & 0xff);
          out_fp8[rb + 16] = (u8)((u01 >> 8) & 0xff);
          out_fp8[rb + 32] = (u8)(u23 & 0xff);
          out_fp8[rb + 48] = (u8)((u23 >> 8) & 0xff);
        }
      }
    }
  }
}

// ---------------- head GEMM 128x64 tile, 256 threads ----------------
// Same 2-phase double-buffer transform.

__global__ __launch_bounds__(256) void gemm64(
    const u16* __restrict__ A1, int lda1, int Ktot, const u16* __restrict__ Bt,
    const float* __restrict__ bias, float* __restrict__ out_f32, int ldof, int M) {
  __shared__ u16 lA[2][128 * 32];
  __shared__ u16 lB[2][64 * 32];
  const int tid = threadIdx.x;
  const int lane = tid & 63;
  const int wv = tid >> 6;
  const int wm = (wv >> 1) * 64;
  const int wn = (wv & 1) * 32;
  const int m0 = blockIdx.x * 128;
  const int r15 = lane & 15;
  const int quad = lane >> 4;

  auto stage = [&](int kk, int b) {
#pragma unroll
    for (int i = 0; i < 2; ++i) {
      int li = tid + i * 256;
      g2l16(A1 + (size_t)(m0 + (li >> 2)) * lda1 + kk + (li & 3) * 8, &lA[b][li * 8]);
    }
    g2l16(Bt + (size_t)(tid >> 2) * Ktot + (kk + (tid & 3) * 8), &lB[b][tid * 8]);
  };

  f32x4 acc[4][2];
#pragma unroll
  for (int i = 0; i < 4; ++i)
#pragma unroll
    for (int j = 0; j < 2; ++j) acc[i][j] = (f32x4){0.f, 0.f, 0.f, 0.f};

  stage(0, 0);
  __syncthreads();
  const int ntk = Ktot >> 5;
  for (int t = 0; t < ntk; ++t) {
    const int cur = t & 1;
    if (t + 1 < ntk) stage((t + 1) * 32, cur ^ 1);
    frag8 af[4], bfr[2];
#pragma unroll
    for (int mt = 0; mt < 4; ++mt)
      af[mt] = *(const frag8*)&lA[cur][(wm + mt * 16 + r15) * 32 + quad * 8];
#pragma unroll
    for (int nt = 0; nt < 2; ++nt)
      bfr[nt] = *(const frag8*)&lB[cur][(wn + nt * 16 + r15) * 32 + quad * 8];
#pragma unroll
    for (int mt = 0; mt < 4; ++mt)
#pragma unroll
      for (int nt = 0; nt < 2; ++nt)
        acc[mt][nt] =
            __builtin_amdgcn_mfma_f32_16x16x32_bf16(af[mt], bfr[nt], acc[mt][nt], 0, 0, 0);
    __syncthreads();
  }

#pragma unroll
  for (int mt = 0; mt < 4; ++mt) {
    int rbase = m0 + wm + mt * 16 + quad * 4;
#pragma unroll
    for (int r = 0; r < 4; ++r) {
      int row = rbase + r;
      if (row < M) {
#pragma unroll
        for (int nt = 0; nt < 2; ++nt) {
          int c = wn + nt * 16 + r15;
          out_f32[(size_t)row * ldof + c] = acc[mt][nt][r] + bias[c];
        }
      }
    }
  }
}

// ---------------- launch ----------------

extern "C" void kernel_launch(void* const* d_in, const int* in_sizes, int n_in, void* d_out,
                              int out_size, void* d_ws, size_t ws_size, hipStream_t stream) {
  const float* x = (const float*)d_in[0];
  const float* W1r = (const float*)d_in[1];
  const float* b1 = (const float*)d_in[2];
  const float* W1o = (const float*)d_in[3];
  const float* W2r = (const float*)d_in[4];
  const float* b2 = (const float*)d_in[5];
  const float* W2o = (const float*)d_in[6];
  const float* W3r = (const float*)d_in[7];
  const float* b3 = (const float*)d_in[8];
  const float* W3o = (const float*)d_in[9];
  const float* Wl = (const float*)d_in[10];
  const float* bl = (const float*)d_in[11];
  const int* src = (const int*)d_in[12];
  const int* dst = src + NE;

  size_t off = 0;
  char* ws = (char*)d_ws;
  auto take = [&](size_t bytes) -> void* {
    void* p = ws + off;
    off = (off + bytes + 255) & ~(size_t)255;
    return p;
  };
  u16* h13 = (u16*)take((size_t)MPAD * 512 * 2);   // h1, later h3 (bf16)
  u16* h2 = (u16*)take((size_t)MPAD * 512 * 2);    // h2 (bf16)
  u16* aggB = (u16*)take((size_t)MPAD * 512 * 2);  // layer1: aggx[node][256]; later agg512
  u16* aggx = aggB;
  u8* hfp8 = (u8*)take((size_t)MPAD * 512);        // h1 fp8, reused for h2 fp8
  float* scb = (float*)take((size_t)MPAD * 2 * 4); // per (row, half) scales
  u16* wt1 = (u16*)take((size_t)512 * 256 * 2);
  u16* wt2 = (u16*)take((size_t)512 * 1024 * 2);
  u16* wt3 = (u16*)take((size_t)512 * 1024 * 2);
  u16* wtl = (u16*)take((size_t)64 * 512 * 2);
  u32* region = (u32*)take((size_t)NBKT * CAP * 4);
  int* gcur = (int*)take(128 * 4);
  int* bbase = (int*)take(128 * 4);
  int* rs = (int*)take((size_t)(NN + 1) * 4);
  u16* csr = (u16*)take((size_t)NE * 2);

  float* out_logits = (float*)d_out;
  float* out_embed = out_logits + (size_t)NN * 64;

  // binned CSR build
  zero_i32<<<1, 128, 0, stream>>>(gcur, NBKT);
  p1bin<<<(NE + 2047) / 2048, 256, 0, stream>>>(src, dst, gcur, region, NE);
  scan98<<<1, 64, 0, stream>>>(gcur, bbase, rs);
  p2build<<<NBKT, 256, 0, stream>>>(region, gcur, bbase, rs, csr);

  // conversions
  f2bf_x<<<(NN * 32 + 255) / 256, 256, 0, stream>>>((const float4*)x, aggx, NN * 32);
  wtrans<<<(512 * 256 + 255) / 256, 256, 0, stream>>>(W1r, 128, W1o, 128, 512, wt1);
  wtrans<<<(512 * 1024 + 255) / 256, 256, 0, stream>>>(W2r, 512, W2o, 512, 512, wt2);
  wtrans<<<(512 * 1024 + 255) / 256, 256, 0, stream>>>(W3r, 512, W3o, 512, 512, wt3);
  wtrans<<<(64 * 512 + 255) / 256, 256, 0, stream>>>(Wl, 512, Wl, 0, 64, wtl);

  // layer 1: agg(x) -> aggx[:,0:128]; h1 = relu([agg|x] @ W1 + b1) -> bf16 + fp8
  agg_bf128<<<(NN + 3) / 4, 256, 0, stream>>>(aggx + 128, 256, aggx, 256, rs, csr, NN);
  gemm256<<<dim3(2, GRID_M), 512, 0, stream>>>(aggx, 256, aggx, 256, 256, 256, wt1, b1, 1,
                                               h13, 512, (float*)nullptr, 0, hfp8, scb, NN);
  // layer 2: fp8 gather of h1; h2 -> bf16 + fp8
  agg_fp8<<<(NN + 3) / 4, 256, 0, stream>>>(hfp8, scb, aggB, rs, csr, NN);
  gemm256<<<dim3(2, GRID_M), 512, 0, stream>>>(aggB, 512, h13, 512, 512, 1024, wt2, b2, 1,
                                               h2, 512, (float*)nullptr, 0, hfp8, scb, NN);
  // layer 3: fp8 gather of h2; h3 -> bf16 + f32 embed
  agg_fp8<<<(NN + 3) / 4, 256, 0, stream>>>(hfp8, scb, aggB, rs, csr, NN);
  gemm256<<<dim3(2, GRID_M), 512, 0, stream>>>(aggB, 512, h2, 512, 512, 1024, wt3, b3, 1,
                                               h13, 512, out_embed, 512, (u8*)nullptr,
                                               (float*)nullptr, NN);
  // head
  gemm64<<<GRID_M, 256, 0, stream>>>(h13, 512, 512, wtl, bl, out_logits, 64, NN);
}